// Round 1
// baseline (734.234 us; speedup 1.0000x reference)
//
#include <hip/hip_runtime.h>
#include <math.h>

namespace {

constexpr int kB = 64;
constexpr int kN = 4096;
constexpr int kM = 128;
constexpr int kH = 512;
constexpr int kE = 256;
constexpr int kO = 256;
constexpr int kGates = 4 * kH;      // 2048
constexpr int kCatW = 3 * kM + kH;  // 896
constexpr int kPRow = 1600;         // padded 1572
constexpr int kWN = kB * kN;
constexpr int GRID = 256;
constexpr int TPB = 512;
constexpr float kLog2e = 1.4426950408889634f;

__device__ __forceinline__ float sigm_(float x) { return 1.f / (1.f + expf(-x)); }
__device__ __forceinline__ float softplus_(float x) { return x > 20.f ? x : log1pf(expf(x)); }

struct Args {
  const float *x, *h_prev, *c_prev, *bank, *read_w_prev, *write_w_prev;
  const float *W_ih, *W_hh, *b_ih, *b_hh, *read_W, *read_b, *write_W, *write_b, *out_W, *out_b;
  float *out;
  float *gates0, *gates1, *hbuf, *praw0, *praw1, *cat;
  float *kwb, *krb, *evb, *avb, *scal, *sdot, *wpack, *mA, *mB;
  unsigned *cnt;
};

union SMem {
  struct { float At[64 * 20]; float Wt[64 * 65]; } g;   // gates/proj tiles
  struct { float wb[kN]; float red[8]; } a;             // addressing
  struct { float nred[4][2]; } s;                       // split norms
  struct { float rl[2 * kM]; } r;                       // passB/C read reduce
  struct { float As[64 * 72]; float Ws[64 * 72]; } o;   // out GEMM tiles
};

// Monotonic-counter grid barrier. Safe: 256 blocks x 512 thr with VGPR<=256
// (enforced by __launch_bounds__(512,2)) always fully co-resident on 256 CUs.
__device__ __forceinline__ void gsync(unsigned* cnt, unsigned target) {
  __syncthreads();
  if (threadIdx.x == 0) {
    __threadfence();           // publish this block's stores (L2 writeback)
    atomicAdd(cnt, 1u);        // device-scope
    while (__hip_atomic_load(cnt, __ATOMIC_ACQUIRE, __HIP_MEMORY_SCOPE_AGENT) < target)
      __builtin_amdgcn_s_sleep(8);
    __threadfence();           // invalidate stale caches before reads
  }
  __syncthreads();
}

// 512-thread addressing core, 8 elems/thread (N=4096)
__device__ void addr_core8(int tid, float* loc, const float* sc, const float* __restrict__ wp,
                           float* wb, float* red) {
  const float g = sc[1], r = sc[2];
  const float s0 = sc[3], s1c = sc[4], s2 = sc[5];
  const int lane = tid & 63, wid = tid >> 6;  // wid 0..7
  __syncthreads();
  float mx = loc[0];
#pragma unroll
  for (int i = 1; i < 8; i++) mx = fmaxf(mx, loc[i]);
#pragma unroll
  for (int m = 1; m < 64; m <<= 1) mx = fmaxf(mx, __shfl_xor(mx, m, 64));
  if (lane == 0) red[wid] = mx;
  __syncthreads();
  mx = red[0];
#pragma unroll
  for (int k = 1; k < 8; k++) mx = fmaxf(mx, red[k]);
  float sum = 0.f;
#pragma unroll
  for (int i = 0; i < 8; i++) { loc[i] = exp2f((loc[i] - mx) * kLog2e); sum += loc[i]; }
#pragma unroll
  for (int m = 1; m < 64; m <<= 1) sum += __shfl_xor(sum, m, 64);
  __syncthreads();
  if (lane == 0) red[wid] = sum;
  __syncthreads();
  sum = red[0];
#pragma unroll
  for (int k = 1; k < 8; k++) sum += red[k];
  const float inv = 1.f / sum;
  const float omg = 1.f - g;
#pragma unroll
  for (int i = 0; i < 8; i++) {
    int n = tid + i * TPB;
    wb[n] = loc[i] * inv + omg * wp[n];
  }
  __syncthreads();
  float ssum = 0.f;
#pragma unroll
  for (int i = 0; i < 8; i++) {
    int n = tid + i * TPB;
    float sh = s0 * wb[(n + kN - 1) & (kN - 1)] + s1c * wb[n] + s2 * wb[(n + 1) & (kN - 1)];
    float y = (sh > 0.f) ? exp2f(r * log2f(sh)) : 0.f;
    loc[i] = y;
    ssum += y;
  }
#pragma unroll
  for (int m = 1; m < 64; m <<= 1) ssum += __shfl_xor(ssum, m, 64);
  __syncthreads();
  if (lane == 0) red[wid] = ssum;
  __syncthreads();
  ssum = red[0];
#pragma unroll
  for (int k = 1; k < 8; k++) ssum += red[k];
  const float invs = 1.f / (ssum + 1e-8f);
#pragma unroll
  for (int i = 0; i < 8; i++) loc[i] *= invs;
  __syncthreads();
}

__global__ __launch_bounds__(TPB, 2) void mega(Args P) {
  const int bid = blockIdx.x;
  const int tid = threadIdx.x;
  __shared__ SMem sm;

  // =============== Phase G: gates GEMM, 2-way k-split (256 blocks) ===============
  {
    const int khalf = bid >> 7;
    const int unit = bid & 127;
    const int b0 = (unit >> 5) * 16;
    const int j0 = (unit & 31) * 64;
    const int jg = tid & 63;
    const int bq2 = (tid >> 6) * 2;
    float acc0 = 0.f, acc1 = 0.f;
    for (int kc6 = 0; kc6 < 6; kc6++) {
      const int kc = khalf * 6 + kc6;
      const bool isx = kc < 4;
      const float* A = isx ? P.x : P.h_prev;
      const float* W = isx ? P.W_ih : P.W_hh;
      const int lda = isx ? kE : kH;
      const int k0 = (isx ? kc : (kc - 4)) * 64;
      __syncthreads();
      {  // A tile: 16 b x 64 k
        int bb = tid >> 5;
        int kk = (tid & 31) * 2;
        float2 v = *(const float2*)(A + (size_t)(b0 + bb) * lda + k0 + kk);
        sm.g.At[(kk + 0) * 20 + bb] = v.x;
        sm.g.At[(kk + 1) * 20 + bb] = v.y;
      }
#pragma unroll
      for (int i = 0; i < 2; i++) {  // W tile: 64 j x 64 k
        int idx = tid + i * 512;
        int jj = idx >> 4;
        int kk = (idx & 15) * 4;
        float4 w = *(const float4*)(W + (size_t)(j0 + jj) * lda + k0 + kk);
        sm.g.Wt[(kk + 0) * 65 + jj] = w.x; sm.g.Wt[(kk + 1) * 65 + jj] = w.y;
        sm.g.Wt[(kk + 2) * 65 + jj] = w.z; sm.g.Wt[(kk + 3) * 65 + jj] = w.w;
      }
      __syncthreads();
#pragma unroll 4
      for (int k = 0; k < 64; k++) {
        float2 av = *(const float2*)&sm.g.At[k * 20 + bq2];
        float wv = sm.g.Wt[k * 65 + jg];
        acc0 += av.x * wv; acc1 += av.y * wv;
      }
    }
    float* gd = khalf ? P.gates1 : P.gates0;
    gd[(size_t)(b0 + bq2 + 0) * kGates + j0 + jg] = acc0;
    gd[(size_t)(b0 + bq2 + 1) * kGates + j0 + jg] = acc1;
  }
  gsync(P.cnt, GRID * 1);

  // =============== Phase H: LSTM h + out/cat init ===============
  if (bid < 64) {
    const int b = bid, kk = tid;
    const float* g0 = P.gates0 + (size_t)b * kGates;
    const float* g1 = P.gates1 + (size_t)b * kGates;
    float i_ = g0[kk] + g1[kk] + P.b_ih[kk] + P.b_hh[kk];
    float f_ = g0[512 + kk] + g1[512 + kk] + P.b_ih[512 + kk] + P.b_hh[512 + kk];
    float gg = g0[1024 + kk] + g1[1024 + kk] + P.b_ih[1024 + kk] + P.b_hh[1024 + kk];
    float o_ = g0[1536 + kk] + g1[1536 + kk] + P.b_ih[1536 + kk] + P.b_hh[1536 + kk];
    float c = sigm_(f_) * P.c_prev[(size_t)b * kH + kk] + sigm_(i_) * tanhf(gg);
    float h = sigm_(o_) * tanhf(c);
    P.hbuf[(size_t)b * kH + kk] = h;
    P.cat[(size_t)b * kCatW + 3 * kM + kk] = h;
  } else if (bid < 80) {  // out = bias
#pragma unroll
    for (int q = 0; q < 2; q++) {
      int i = (bid - 64) * 1024 + tid + q * 512;
      P.out[i] = P.out_b[i & (kO - 1)];
    }
  } else if (bid < 96) {  // cat[:, 0:384) = 0
#pragma unroll
    for (int q = 0; q < 3; q++) {
      int i = (bid - 80) * 1536 + tid + q * 512;
      P.cat[(size_t)(i / 384) * kCatW + (i % 384)] = 0.f;
    }
  }
  gsync(P.cnt, GRID * 2);

  // =============== Phase P: head projections GEMM, 2-way k-split (200 blocks) ===============
  if (bid < 200) {
    const int kh = bid / 100;
    const int u = bid % 100;
    const int b0 = (u / 25) * 16;
    const int j0 = (u % 25) * 64;
    const int jg = tid & 63;
    const int bq2 = (tid >> 6) * 2;
    float acc0 = 0.f, acc1 = 0.f;
    for (int kc4 = 0; kc4 < 4; kc4++) {
      const int k0 = (kh * 4 + kc4) * 64;
      __syncthreads();
      {  // h tile: 16 b x 64 k
        int bb = tid >> 5;
        int kk = (tid & 31) * 2;
        float2 v = *(const float2*)(P.hbuf + (size_t)(b0 + bb) * kH + k0 + kk);
        sm.g.At[(kk + 0) * 20 + bb] = v.x;
        sm.g.At[(kk + 1) * 20 + bb] = v.y;
      }
#pragma unroll
      for (int i = 0; i < 2; i++) {  // W tile: 64 j x 64 k
        int idx = tid + i * 512;
        int jj = idx >> 4;
        int kk = (idx & 15) * 4;
        int j = j0 + jj;
        float4 w = make_float4(0.f, 0.f, 0.f, 0.f);
        if (j < 1170)      w = *(const float4*)(P.write_W + (size_t)j * kH + k0 + kk);
        else if (j < 1572) w = *(const float4*)(P.read_W + (size_t)(j - 1170) * kH + k0 + kk);
        sm.g.Wt[(kk + 0) * 65 + jj] = w.x; sm.g.Wt[(kk + 1) * 65 + jj] = w.y;
        sm.g.Wt[(kk + 2) * 65 + jj] = w.z; sm.g.Wt[(kk + 3) * 65 + jj] = w.w;
      }
      __syncthreads();
#pragma unroll 4
      for (int k = 0; k < 64; k++) {
        float2 av = *(const float2*)&sm.g.At[k * 20 + bq2];
        float wv = sm.g.Wt[k * 65 + jg];
        acc0 += av.x * wv; acc1 += av.y * wv;
      }
    }
    float* pd = kh ? P.praw1 : P.praw0;
    if (j0 + jg < 1572) {
      pd[(size_t)(b0 + bq2 + 0) * kPRow + j0 + jg] = acc0;
      pd[(size_t)(b0 + bq2 + 1) * kPRow + j0 + jg] = acc1;
    }
  }
  gsync(P.cnt, GRID * 3);

  // =============== Phase S: split params (6 heads in parallel) + sdots ===============
  if (bid < kB) {
    const int b = bid;
    const int m = tid & 127;
    const int hg = tid >> 7;  // 0..3
    const float* pr0 = P.praw0 + (size_t)b * kPRow;
    const float* pr1 = P.praw1 + (size_t)b * kPRow;
    {  // iter 0: heads {W0, W1, W2, R0}
      const bool isw = hg < 3;
      const int base = isw ? hg * 390 : 1170;
      const float* bias = isw ? (P.write_b + hg * 390) : P.read_b;
      const int slot = isw ? hg : 3;
      float kv = pr0[base + m] + pr1[base + m] + bias[m];
      if (isw) {
        P.kwb[((size_t)hg * kB + b) * kM + m] = kv;
        P.evb[((size_t)hg * kB + b) * kM + m] =
            sigm_(pr0[base + 134 + m] + pr1[base + 134 + m] + bias[134 + m]);
        P.avb[((size_t)hg * kB + b) * kM + m] =
            pr0[base + 262 + m] + pr1[base + 262 + m] + bias[262 + m];
      } else {
        P.krb[((size_t)0 * kB + b) * kM + m] = kv;
      }
      float sq = kv * kv;
#pragma unroll
      for (int mm = 1; mm < 64; mm <<= 1) sq += __shfl_xor(sq, mm, 64);
      if ((tid & 63) == 0) sm.s.nred[hg][m >> 6] = sq;
      __syncthreads();
      if (m == 0) {
        float* s = P.scal + ((size_t)slot * kB + b) * 8;
        s[0] = softplus_(pr0[base + 128] + pr1[base + 128] + bias[128]);
        s[1] = sigm_(pr0[base + 129] + pr1[base + 129] + bias[129]);
        s[2] = 1.f + softplus_(pr0[base + 133] + pr1[base + 133] + bias[133]);
        float x0 = pr0[base + 130] + pr1[base + 130] + bias[130];
        float x1 = pr0[base + 131] + pr1[base + 131] + bias[131];
        float x2 = pr0[base + 132] + pr1[base + 132] + bias[132];
        float mx = fmaxf(x0, fmaxf(x1, x2));
        float e0 = expf(x0 - mx), e1 = expf(x1 - mx), e2 = expf(x2 - mx);
        float si = 1.f / (e0 + e1 + e2);
        s[3] = e0 * si; s[4] = e1 * si; s[5] = e2 * si;
        s[6] = sqrtf(sm.s.nred[hg][0] + sm.s.nred[hg][1]);
      }
      __syncthreads();
    }
    {  // iter 1: heads {R1, R2} on hg 0,1 (hg 2,3 dummy)
      const int j = (hg < 2) ? hg + 1 : 2;
      const bool act = hg < 2;
      const int base = 1170 + j * 134;
      const float* bias = P.read_b + j * 134;
      const int slot = 3 + j;
      float kv = pr0[base + m] + pr1[base + m] + bias[m];
      if (act) P.krb[((size_t)j * kB + b) * kM + m] = kv;
      float sq = kv * kv;
#pragma unroll
      for (int mm = 1; mm < 64; mm <<= 1) sq += __shfl_xor(sq, mm, 64);
      if ((tid & 63) == 0) sm.s.nred[hg][m >> 6] = sq;
      __syncthreads();
      if (m == 0 && act) {
        float* s = P.scal + ((size_t)slot * kB + b) * 8;
        s[0] = softplus_(pr0[base + 128] + pr1[base + 128] + bias[128]);
        s[1] = sigm_(pr0[base + 129] + pr1[base + 129] + bias[129]);
        s[2] = 1.f + softplus_(pr0[base + 133] + pr1[base + 133] + bias[133]);
        float x0 = pr0[base + 130] + pr1[base + 130] + bias[130];
        float x1 = pr0[base + 131] + pr1[base + 131] + bias[131];
        float x2 = pr0[base + 132] + pr1[base + 132] + bias[132];
        float mx = fmaxf(x0, fmaxf(x1, x2));
        float e0 = expf(x0 - mx), e1 = expf(x1 - mx), e2 = expf(x2 - mx);
        float si = 1.f / (e0 + e1 + e2);
        s[3] = e0 * si; s[4] = e1 * si; s[5] = e2 * si;
        s[6] = sqrtf(sm.s.nred[hg][0] + sm.s.nred[hg][1]);
      }
      __syncthreads();
    }
    // sdots: {a0.kr0, a0.kw1, a0.a0, a2.kr2, a2.a2}
    if (tid < 64) {
      const float* a0v = P.avb + ((size_t)0 * kB + b) * kM;
      const float* a2v = P.avb + ((size_t)2 * kB + b) * kM;
      const float* u[5] = {a0v, a0v, a0v, a2v, a2v};
      const float* v[5] = {P.krb + ((size_t)0 * kB + b) * kM,
                           P.kwb + ((size_t)1 * kB + b) * kM,
                           a0v,
                           P.krb + ((size_t)2 * kB + b) * kM,
                           a2v};
#pragma unroll
      for (int d = 0; d < 5; d++) {
        float s = u[d][tid] * v[d][tid] + u[d][tid + 64] * v[d][tid + 64];
#pragma unroll
        for (int mm = 1; mm < 64; mm <<= 1) s += __shfl_xor(s, mm, 64);
        if (tid == 0) P.sdot[b * 8 + d] = s;
      }
    }
  }
  gsync(P.cnt, GRID * 4);

  // =============== Phase A: B0 moments (packed mA[n][12]) ===============
  {
    const int b = bid >> 2, chunk = bid & 3;
    const int lane = tid & 63, wv = tid >> 6, sub = lane >> 4, lm = lane & 15;
    const int m8 = lm * 8;
    float kw0r[8], kr0r[8], kw1r[8], a0r[8], e0r[8];
#pragma unroll
    for (int t = 0; t < 8; t++) {
      kw0r[t] = P.kwb[((size_t)0 * kB + b) * kM + m8 + t];
      kr0r[t] = P.krb[((size_t)0 * kB + b) * kM + m8 + t];
      kw1r[t] = P.kwb[((size_t)1 * kB + b) * kM + m8 + t];
      a0r[t]  = P.avb[((size_t)0 * kB + b) * kM + m8 + t];
      e0r[t]  = P.evb[((size_t)0 * kB + b) * kM + m8 + t];
    }
    const size_t bbase = (size_t)b * kN * kM;
    const size_t brow = (size_t)b * kN;
    const int row0 = chunk * 1024 + wv * 4 + sub;
    const float* base = P.bank + bbase + (size_t)row0 * kM + m8;
    float4 pA0 = *(const float4*)(base);
    float4 pA1 = *(const float4*)(base + 4);
    float4 pB0 = *(const float4*)(base + (size_t)32 * kM);
    float4 pB1 = *(const float4*)(base + (size_t)32 * kM + 4);
    for (int it = 0; it < 32; it++) {
      float v[8];
      if ((it & 1) == 0) {
        v[0]=pA0.x; v[1]=pA0.y; v[2]=pA0.z; v[3]=pA0.w; v[4]=pA1.x; v[5]=pA1.y; v[6]=pA1.z; v[7]=pA1.w;
        if (it + 2 < 32) {
          const float* np = base + (size_t)(it + 2) * 32 * kM;
          pA0 = *(const float4*)np; pA1 = *(const float4*)(np + 4);
        }
      } else {
        v[0]=pB0.x; v[1]=pB0.y; v[2]=pB0.z; v[3]=pB0.w; v[4]=pB1.x; v[5]=pB1.y; v[6]=pB1.z; v[7]=pB1.w;
        if (it + 2 < 32) {
          const float* np = base + (size_t)(it + 2) * 32 * kM;
          pB0 = *(const float4*)np; pB1 = *(const float4*)(np + 4);
        }
      }
      const int row = row0 + it * 32;
      float s[10] = {};
#pragma unroll
      for (int t = 0; t < 8; t++) {
        float be = v[t] * e0r[t];
        s[0] += v[t] * kw0r[t];
        s[1] += v[t] * v[t];
        s[2] += v[t] * kr0r[t];
        s[3] += be * kr0r[t];
        s[4] += v[t] * kw1r[t];
        s[5] += be * kw1r[t];
        s[6] += be * v[t];
        s[7] += be * be;
        s[8] += v[t] * a0r[t];
        s[9] += be * a0r[t];
      }
#pragma unroll
      for (int m = 1; m < 16; m <<= 1)
#pragma unroll
        for (int k = 0; k < 10; k++) s[k] += __shfl_xor(s[k], m, 64);
      if (lm == 0) {
        float4* dst = (float4*)(P.mA + (size_t)(brow + row) * 12);
        dst[0] = make_float4(s[0], s[1], s[2], s[3]);
        dst[1] = make_float4(s[4], s[5], s[6], s[7]);
        dst[2] = make_float4(s[8], s[9], 0.f, 0.f);
      }
    }
  }
  gsync(P.cnt, GRID * 5);

  // =============== Phase A12: w0, wr0, w1 -> wpack {0,2,1} ===============
  if (bid < kB) {
    const int b = bid;
    const size_t brow = (size_t)b * kN;
    float loc[8], w0r[8], q1r[8];
    {  // write head 0 on B0
      const float* sc = P.scal + ((size_t)0 * kB + b) * 8;
      const float beta = sc[0], kn = sc[6];
#pragma unroll
      for (int i = 0; i < 8; i++) {
        const float* mp = P.mA + (size_t)(brow + tid + i * TPB) * 12;
        float4 q0 = *(const float4*)mp;
        loc[i] = beta * q0.x / fmaxf(sqrtf(fmaxf(q0.y, 0.f)) * kn, 1e-8f);
      }
      addr_core8(tid, loc, sc, P.write_w_prev + brow, sm.a.wb, sm.a.red);
#pragma unroll
      for (int i = 0; i < 8; i++) {
        P.wpack[(size_t)(brow + tid + i * TPB) * 8 + 0] = loc[i];
        w0r[i] = loc[i];
      }
    }
    {  // read head 0 on B1 (expanded)
      const float* sc = P.scal + ((size_t)3 * kB + b) * 8;
      const float beta = sc[0], kn = sc[6];
      const float sa0kr0 = P.sdot[b * 8 + 0], sa0a0 = P.sdot[b * 8 + 2];
#pragma unroll
      for (int i = 0; i < 8; i++) {
        const float* mp = P.mA + (size_t)(brow + tid + i * TPB) * 12;
        float4 q0 = *(const float4*)mp;
        float4 q1 = *(const float4*)(mp + 4);
        float4 q2 = *(const float4*)(mp + 8);
        float w0 = w0r[i], w0q = w0 * w0;
        float q1v = q0.y - 2.f * w0 * q1.z + w0q * q1.w + 2.f * w0 * q2.x
                  - 2.f * w0q * q2.y + w0q * sa0a0;
        q1r[i] = q1v;
        float d = q0.z - w0 * q0.w + w0 * sa0kr0;
        loc[i] = beta * d / fmaxf(sqrtf(fmaxf(q1v, 0.f)) * kn, 1e-8f);
      }
      addr_core8(tid, loc, sc, P.read_w_prev + brow, sm.a.wb, sm.a.red);
#pragma unroll
      for (int i = 0; i < 8; i++)
        P.wpack[(size_t)(brow + tid + i * TPB) * 8 + 2] = loc[i];
    }
    {  // write head 1 on B1 (expanded)
      const float* sc = P.scal + ((size_t)1 * kB + b) * 8;
      const float beta = sc[0], kn = sc[6];
      const float sa0kw1 = P.sdot[b * 8 + 1];
#pragma unroll
      for (int i = 0; i < 8; i++) {
        const float* mp = P.mA + (size_t)(brow + tid + i * TPB) * 12;
        float4 q1 = *(const float4*)(mp + 4);
        float w0 = w0r[i];
        float d = q1.x - w0 * q1.y + w0 * sa0kw1;
        loc[i] = beta * d / fmaxf(sqrtf(fmaxf(q1r[i], 0.f)) * kn, 1e-8f);
      }
      addr_core8(tid, loc, sc, P.write_w_prev + (size_t)kWN + brow, sm.a.wb, sm.a.red);
#pragma unroll
      for (int i = 0; i < 8; i++)
        P.wpack[(size_t)(brow + tid + i * TPB) * 8 + 1] = loc[i];
    }
  }
  gsync(P.cnt, GRID * 6);

  // =============== Phase B: chain(w0,w1), read0, B2 moments (mB[n][12]) ===============
  {
    const int b = bid >> 2, chunk = bid & 3;
    const int lane = tid & 63, wv = tid >> 6, sub = lane >> 4, lm = lane & 15;
    const int m8 = lm * 8;
    float e0r[8], a0r[8], e1r[8], a1r[8], kr1r[8], kw2r[8], kr2r[8], e2r[8], a2r[8];
#pragma unroll
    for (int t = 0; t < 8; t++) {
      e0r[t]  = P.evb[((size_t)0 * kB + b) * kM + m8 + t];
      a0r[t]  = P.avb[((size_t)0 * kB + b) * kM + m8 + t];
      e1r[t]  = P.evb[((size_t)1 * kB + b) * kM + m8 + t];
      a1r[t]  = P.avb[((size_t)1 * kB + b) * kM + m8 + t];
      kr1r[t] = P.krb[((size_t)1 * kB + b) * kM + m8 + t];
      kw2r[t] = P.kwb[((size_t)2 * kB + b) * kM + m8 + t];
      kr2r[t] = P.krb[((size_t)2 * kB + b) * kM + m8 + t];
      e2r[t]  = P.evb[((size_t)2 * kB + b) * kM + m8 + t];
      a2r[t]  = P.avb[((size_t)2 * kB + b) * kM + m8 + t];
    }
    float racc[8] = {};
    if (tid < kM) sm.r.rl[tid] = 0.f;
    const size_t bbase = (size_t)b * kN * kM;
    const size_t brow = (size_t)b * kN;
    const int row0 = chunk * 1024 + wv * 4 + sub;
    const float* base = P.bank + bbase + (size_t)row0 * kM + m8;
    const float* wbase = P.wpack + (size_t)(brow + row0) * 8;
    float4 pA0 = *(const float4*)(base);
    float4 pA1 = *(const float4*)(base + 4);
    float4 wA  = *(const float4*)(wbase);
    float4 pB0 = *(const float4*)(base + (size_t)32 * kM);
    float4 pB1 = *(const float4*)(base + (size_t)32 * kM + 4);
    float4 wB  = *(const float4*)(wbase + (size_t)32 * 8);
    for (int it = 0; it < 32; it++) {
      float v[8];
      float w0, w1, wr0;
      if ((it & 1) == 0) {
        v[0]=pA0.x; v[1]=pA0.y; v[2]=pA0.z; v[3]=pA0.w; v[4]=pA1.x; v[5]=pA1.y; v[6]=pA1.z; v[7]=pA1.w;
        w0 = wA.x; w1 = wA.y; wr0 = wA.z;
        if (it + 2 < 32) {
          const float* np = base + (size_t)(it + 2) * 32 * kM;
          pA0 = *(const float4*)np; pA1 = *(const float4*)(np + 4);
          wA = *(const float4*)(wbase + (size_t)(it + 2) * 32 * 8);
        }
      } else {
        v[0]=pB0.x; v[1]=pB0.y; v[2]=pB0.z; v[3]=pB0.w; v[4]=pB1.x; v[5]=pB1.y; v[6]=pB1.z; v[7]=pB1.w;
        w0 = wB.x; w1 = wB.y; wr0 = wB.z;
        if (it + 2 < 32) {
          const float* np = base + (size_t)(it + 2) * 32 * kM;
          pB0 = *(const float4*)np; pB1 = *(const float4*)(np + 4);
          wB = *(const float4*)(wbase + (size_t)(it + 2) * 32 * 8);
        }
      }
      const int row = row0 + it * 32;
#pragma unroll
      for (int t = 0; t < 8; t++) {
        v[t] += w0 * (a0r[t] - e0r[t] * v[t]);  // -> B1
        racc[t] += wr0 * v[t];                   // read0 from B1
        v[t] += w1 * (a1r[t] - e1r[t] * v[t]);  // -> B2
      }
      float s[9] = {};
#pragma unroll
      for (int t = 0; t < 8; t++) {
        float ve = v[t] * e2r[t];
        s[0] += v[t] * kr1r[t];
        s[1] += v[t] * kw2r[t];
        s[2] += v[t] * v[t];
        s[3] += v[t] * kr2r[t];
        s[4] += ve * kr2r[t];
        s[5] += ve * v[t];
        s[6] += ve * ve;
        s[7] += v[t] * a2r[t];
        s[8] += ve * a2r[t];
      }
#pragma unroll
      for (int m = 1; m < 16; m <<= 1)
#pragma unroll
        for (int k = 0; k < 9; k++) s[k] += __shfl_xor(s[k], m, 64);
      if (lm == 0) {
        float4* dst = (float4*)(P.mB + (size_t)(brow + row) * 12);
        dst[0] = make_float4(s[0], s[1], s[2], s[3]);
        dst[1] = make_float4(s[4], s[5], s[6], s[7]);
        dst[2] = make_float4(s[8], 0.f, 0.f, 0.f);
      }
    }
    __syncthreads();
#pragma unroll
    for (int t = 0; t < 8; t++) {
      racc[t] += __shfl_xor(racc[t], 16, 64);
      racc[t] += __shfl_xor(racc[t], 32, 64);
    }
    if (sub == 0) {
#pragma unroll
      for (int t = 0; t < 8; t++) atomicAdd(&sm.r.rl[m8 + t], racc[t]);
    }
    __syncthreads();
    if (tid < kM) atomicAdd(&P.cat[(size_t)b * kCatW + tid], sm.r.rl[tid]);
  }
  gsync(P.cnt, GRID * 7);

  // =============== Phase A34: wr1, w2, wr2 -> wpack {4,3,5} ===============
  if (bid < kB) {
    const int b = bid;
    const size_t brow = (size_t)b * kN;
    float loc[8], w2r[8];
    {  // read head 1 on B2
      const float* sc = P.scal + ((size_t)4 * kB + b) * 8;
      const float beta = sc[0], kn = sc[6];
#pragma unroll
      for (int i = 0; i < 8; i++) {
        const float* mp = P.mB + (size_t)(brow + tid + i * TPB) * 12;
        float4 q0 = *(const float4*)mp;
        loc[i] = beta * q0.x / fmaxf(sqrtf(fmaxf(q0.z, 0.f)) * kn, 1e-8f);
      }
      addr_core8(tid, loc, sc, P.read_w_prev + (size_t)kWN + brow, sm.a.wb, sm.a.red);
#pragma unroll
      for (int i = 0; i < 8; i++)
        P.wpack[(size_t)(brow + tid + i * TPB) * 8 + 4] = loc[i];
    }
    {  // write head 2 on B2
      const float* sc = P.scal + ((size_t)2 * kB + b) * 8;
      const float beta = sc[0], kn = sc[6];
#pragma unroll
      for (int i = 0; i < 8; i++) {
        const float* mp = P.mB + (size_t)(brow + tid + i * TPB) * 12;
        float4 q0 = *(const float4*)mp;
        loc[i] = beta * q0.y / fmaxf(sqrtf(fmaxf(q0.z, 0.f)) * kn, 1e-8f);
      }
      addr_core8(tid, loc, sc, P.write_w_prev + (size_t)2 * kWN + brow, sm.a.wb, sm.a.red);
#pragma unroll
      for (int i = 0; i < 8; i++) {
        P.wpack[(size_t)(brow + tid + i * TPB) * 8 + 3] = loc[i];
        w2r[i] = loc[i];
      }
    }
    {  // read head 2 on B3 (expanded)
      const float* sc = P.scal + ((size_t)5 * kB + b) * 8;
      const float beta = sc[0], kn = sc[6];
      const float sa2kr2 = P.sdot[b * 8 + 3], sa2a2 = P.sdot[b * 8 + 4];
#pragma unroll
      for (int i = 0; i < 8; i++) {
        const float* mp = P.mB + (size_t)(brow + tid + i * TPB) * 12;
        float4 q0 = *(const float4*)mp;
        float4 q1 = *(const float4*)(mp + 4);
        float4 q2 = *(const float4*)(mp + 8);
        float w2 = w2r[i], w2q = w2 * w2;
        float q3 = q0.z - 2.f * w2 * q1.y + w2q * q1.z + 2.f * w2 * q1.w
                 - 2.f * w2q * q2.x + w2q * sa2a2;
        float d = q0.w - w2 * q1.x + w2 * sa2kr2;
        loc[i] = beta * d / fmaxf(sqrtf(fmaxf(q3, 0.f)) * kn, 1e-8f);
      }
      addr_core8(tid, loc, sc, P.read_w_prev + (size_t)2 * kWN + brow, sm.a.wb, sm.a.red);
#pragma unroll
      for (int i = 0; i < 8; i++)
        P.wpack[(size_t)(brow + tid + i * TPB) * 8 + 5] = loc[i];
    }
  }
  gsync(P.cnt, GRID * 8);

  // =============== Phase C: chain(w0,w1,w2), read1 from B2, read2 from B3 ===============
  {
    const int b = bid >> 2, chunk = bid & 3;
    const int lane = tid & 63, wv = tid >> 6, sub = lane >> 4, lm = lane & 15;
    const int m8 = lm * 8;
    float e_r[3][8], a_r[3][8];
#pragma unroll
    for (int j = 0; j < 3; j++)
#pragma unroll
      for (int t = 0; t < 8; t++) {
        e_r[j][t] = P.evb[((size_t)j * kB + b) * kM + m8 + t];
        a_r[j][t] = P.avb[((size_t)j * kB + b) * kM + m8 + t];
      }
    float racc1[8] = {}, racc2[8] = {};
    if (tid < kM) { sm.r.rl[tid] = 0.f; sm.r.rl[kM + tid] = 0.f; }
    const size_t bbase = (size_t)b * kN * kM;
    const size_t brow = (size_t)b * kN;
    const int row0 = chunk * 1024 + wv * 4 + sub;
    const float* base = P.bank + bbase + (size_t)row0 * kM + m8;
    const float* wbase = P.wpack + (size_t)(brow + row0) * 8;
    float4 pA0 = *(const float4*)(base);
    float4 pA1 = *(const float4*)(base + 4);
    float4 wAa = *(const float4*)(wbase);
    float4 wAb = *(const float4*)(wbase + 4);
    float4 pB0 = *(const float4*)(base + (size_t)32 * kM);
    float4 pB1 = *(const float4*)(base + (size_t)32 * kM + 4);
    float4 wBa = *(const float4*)(wbase + (size_t)32 * 8);
    float4 wBb = *(const float4*)(wbase + (size_t)32 * 8 + 4);
    for (int it = 0; it < 32; it++) {
      float v[8];
      float w0, w1, w2, wr1, wr2;
      if ((it & 1) == 0) {
        v[0]=pA0.x; v[1]=pA0.y; v[2]=pA0.z; v[3]=pA0.w; v[4]=pA1.x; v[5]=pA1.y; v[6]=pA1.z; v[7]=pA1.w;
        w0 = wAa.x; w1 = wAa.y; w2 = wAa.w; wr1 = wAb.x; wr2 = wAb.y;
        if (it + 2 < 32) {
          const float* np = base + (size_t)(it + 2) * 32 * kM;
          pA0 = *(const float4*)np; pA1 = *(const float4*)(np + 4);
          const float* wp = wbase + (size_t)(it + 2) * 32 * 8;
          wAa = *(const float4*)wp; wAb = *(const float4*)(wp + 4);
        }
      } else {
        v[0]=pB0.x; v[1]=pB0.y; v[2]=pB0.z; v[3]=pB0.w; v[4]=pB1.x; v[5]=pB1.y; v[6]=pB1.z; v[7]=pB1.w;
        w0 = wBa.x; w1 = wBa.y; w2 = wBa.w; wr1 = wBb.x; wr2 = wBb.y;
        if (it + 2 < 32) {
          const float* np = base + (size_t)(it + 2) * 32 * kM;
          pB0 = *(const float4*)np; pB1 = *(const float4*)(np + 4);
          const float* wp = wbase + (size_t)(it + 2) * 32 * 8;
          wBa = *(const float4*)wp; wBb = *(const float4*)(wp + 4);
        }
      }
#pragma unroll
      for (int t = 0; t < 8; t++) {
        v[t] += w0 * (a_r[0][t] - e_r[0][t] * v[t]);  // B1
        v[t] += w1 * (a_r[1][t] - e_r[1][t] * v[t]);  // B2
        racc1[t] += wr1 * v[t];
        v[t] += w2 * (a_r[2][t] - e_r[2][t] * v[t]);  // B3
        racc2[t] += wr2 * v[t];
      }
    }
    __syncthreads();
#pragma unroll
    for (int t = 0; t < 8; t++) {
      racc1[t] += __shfl_xor(racc1[t], 16, 64);
      racc1[t] += __shfl_xor(racc1[t], 32, 64);
      racc2[t] += __shfl_xor(racc2[t], 16, 64);
      racc2[t] += __shfl_xor(racc2[t], 32, 64);
    }
    if (sub == 0) {
#pragma unroll
      for (int t = 0; t < 8; t++) {
        atomicAdd(&sm.r.rl[m8 + t], racc1[t]);
        atomicAdd(&sm.r.rl[kM + m8 + t], racc2[t]);
      }
    }
    __syncthreads();
    if (tid < kM) {
      atomicAdd(&P.cat[(size_t)b * kCatW + kM + tid], sm.r.rl[tid]);
      atomicAdd(&P.cat[(size_t)b * kCatW + 2 * kM + tid], sm.r.rl[kM + tid]);
    }
  }
  gsync(P.cnt, GRID * 9);

  // =============== Phase O: out GEMM (56 blocks, split-k atomic) ===============
  if (bid < 56) {
    const int jt = bid & 3, kt = bid >> 2;  // kt 0..13
    const int j0 = jt * 64, k0 = kt * 64;
    {
      int bb = tid >> 3;
      int kk = (tid & 7) * 8;
      float4 v0 = *(const float4*)(P.cat + (size_t)bb * kCatW + k0 + kk);
      float4 v1 = *(const float4*)(P.cat + (size_t)bb * kCatW + k0 + kk + 4);
      sm.o.As[(kk + 0) * 72 + bb] = v0.x; sm.o.As[(kk + 1) * 72 + bb] = v0.y;
      sm.o.As[(kk + 2) * 72 + bb] = v0.z; sm.o.As[(kk + 3) * 72 + bb] = v0.w;
      sm.o.As[(kk + 4) * 72 + bb] = v1.x; sm.o.As[(kk + 5) * 72 + bb] = v1.y;
      sm.o.As[(kk + 6) * 72 + bb] = v1.z; sm.o.As[(kk + 7) * 72 + bb] = v1.w;
      float4 w0_ = *(const float4*)(P.out_W + (size_t)(j0 + bb) * kCatW + k0 + kk);
      float4 w1_ = *(const float4*)(P.out_W + (size_t)(j0 + bb) * kCatW + k0 + kk + 4);
      sm.o.Ws[(kk + 0) * 72 + bb] = w0_.x; sm.o.Ws[(kk + 1) * 72 + bb] = w0_.y;
      sm.o.Ws[(kk + 2) * 72 + bb] = w0_.z; sm.o.Ws[(kk + 3) * 72 + bb] = w0_.w;
      sm.o.Ws[(kk + 4) * 72 + bb] = w1_.x; sm.o.Ws[(kk + 5) * 72 + bb] = w1_.y;
      sm.o.Ws[(kk + 6) * 72 + bb] = w1_.z; sm.o.Ws[(kk + 7) * 72 + bb] = w1_.w;
    }
    __syncthreads();
    const int b0 = (tid & 15) * 4;
    const int jq = (tid >> 4) * 2;
    float acc[4][2] = {};
#pragma unroll 2
    for (int k = 0; k < 64; k++) {
      float4 av = *(const float4*)&sm.o.As[k * 72 + b0];
      float2 wv = *(const float2*)&sm.o.Ws[k * 72 + jq];
      acc[0][0] += av.x * wv.x; acc[0][1] += av.x * wv.y;
      acc[1][0] += av.y * wv.x; acc[1][1] += av.y * wv.y;
      acc[2][0] += av.z * wv.x; acc[2][1] += av.z * wv.y;
      acc[3][0] += av.w * wv.x; acc[3][1] += av.w * wv.y;
    }
#pragma unroll
    for (int ii = 0; ii < 4; ii++) {
      atomicAdd(&P.out[(size_t)(b0 + ii) * kO + j0 + jq + 0], acc[ii][0]);
      atomicAdd(&P.out[(size_t)(b0 + ii) * kO + j0 + jq + 1], acc[ii][1]);
    }
  }
}

}  // namespace

extern "C" void kernel_launch(void* const* d_in, const int* in_sizes, int n_in,
                              void* d_out, int out_size, void* d_ws, size_t ws_size,
                              hipStream_t stream) {
  Args A_;
  A_.x            = (const float*)d_in[0];
  A_.h_prev       = (const float*)d_in[1];
  A_.c_prev       = (const float*)d_in[2];
  A_.bank         = (const float*)d_in[3];
  A_.read_w_prev  = (const float*)d_in[4];
  A_.write_w_prev = (const float*)d_in[5];
  A_.W_ih         = (const float*)d_in[6];
  A_.W_hh         = (const float*)d_in[7];
  A_.b_ih         = (const float*)d_in[8];
  A_.b_hh         = (const float*)d_in[9];
  A_.read_W       = (const float*)d_in[10];
  A_.read_b       = (const float*)d_in[11];
  A_.write_W      = (const float*)d_in[12];
  A_.write_b      = (const float*)d_in[13];
  A_.out_W        = (const float*)d_in[14];
  A_.out_b        = (const float*)d_in[15];
  A_.out = (float*)d_out;

  float* ws = (float*)d_ws;
  A_.cnt = (unsigned*)d_ws;          // first 256 B: barrier counter
  float* p = ws + 64;
  A_.gates0 = p; p += (size_t)kB * kGates;
  A_.gates1 = p; p += (size_t)kB * kGates;
  A_.hbuf   = p; p += (size_t)kB * kH;
  A_.praw0  = p; p += (size_t)kB * kPRow;
  A_.praw1  = p; p += (size_t)kB * kPRow;
  A_.cat    = p; p += (size_t)kB * kCatW;
  A_.kwb    = p; p += (size_t)3 * kB * kM;
  A_.krb    = p; p += (size_t)3 * kB * kM;
  A_.evb    = p; p += (size_t)3 * kB * kM;
  A_.avb    = p; p += (size_t)3 * kB * kM;
  A_.scal   = p; p += (size_t)6 * kB * 8;
  A_.sdot   = p; p += (size_t)kB * 8;
  A_.wpack  = p; p += (size_t)kWN * 8;
  A_.mA     = p; p += (size_t)kWN * 12;
  A_.mB     = p; p += (size_t)kWN * 12;

  hipMemsetAsync(d_ws, 0, 256, stream);
  mega<<<dim3(GRID), dim3(TPB), 0, stream>>>(A_);

  (void)in_sizes; (void)n_in; (void)out_size; (void)ws_size;
}

// Round 3
// 490.925 us; speedup vs baseline: 1.4956x; 1.4956x over previous
//
#include <hip/hip_runtime.h>
#include <math.h>

namespace {

constexpr int kB = 64;
constexpr int kN = 4096;
constexpr int kM = 128;
constexpr int kH = 512;
constexpr int kE = 256;
constexpr int kO = 256;
constexpr int kGates = 4 * kH;      // 2048
constexpr int kCatW = 3 * kM + kH;  // 896
constexpr int kPRow = 1600;         // padded 1572
constexpr int kWN = kB * kN;
constexpr int GRID = 256;
constexpr int TPB = 512;
constexpr float kLog2e = 1.4426950408889634f;

__device__ __forceinline__ float sigm_(float x) { return 1.f / (1.f + expf(-x)); }
__device__ __forceinline__ float softplus_(float x) { return x > 20.f ? x : log1pf(expf(x)); }

struct Args {
  const float *x, *h_prev, *c_prev, *bank, *read_w_prev, *write_w_prev;
  const float *W_ih, *W_hh, *b_ih, *b_hh, *read_W, *read_b, *write_W, *write_b, *out_W, *out_b;
  float *out;
  float *gates0, *gates1, *praw0, *praw1, *cat;
  float *kwb, *krb, *evb, *avb, *scal, *sdot;
  float *wp0, *wp1, *wp2, *wp3, *wp4, *wp5;
  float *mA, *mB;
  unsigned *cnt;
};

union SMem {
  struct { float At[64 * 20]; float Wt[64 * 65]; } g;   // gates tiles
  struct { float hs[256 * 18]; float Wt[64 * 65]; } p;  // proj: 16-batch h-slice + W tile
  struct { float wb[kN]; float red[8]; } a;             // addressing
  struct { float nred[4][2]; } s;                       // split norms
  struct { float rl[2 * kM]; } r;                       // passB/C read reduce
  struct { float As[64 * 72]; float Ws[64 * 72]; } o;   // out GEMM tiles
};

// Grid barrier. CRITICAL: poll with RELAXED loads (agent-scope relaxed load is
// served at the coherence point, NO per-iteration cache invalidation); one
// release fence (wb) before arrival, one acquire fence (inv) after exit.
// Polling with ACQUIRE semantics emits buffer_inv per poll iteration ->
// continuous L2 invalidation storm from waiting blocks (round-1 evidence:
// 590us, VALUBusy 7.5%, hbm 543 GB/s).
__device__ __forceinline__ void gsync(unsigned* cnt, unsigned target) {
  __syncthreads();
  if (threadIdx.x == 0) {
    __builtin_amdgcn_fence(__ATOMIC_RELEASE, "agent");  // drain + writeback (no inv)
    __hip_atomic_fetch_add(cnt, 1u, __ATOMIC_RELAXED, __HIP_MEMORY_SCOPE_AGENT);
    while (__hip_atomic_load(cnt, __ATOMIC_RELAXED, __HIP_MEMORY_SCOPE_AGENT) < target)
      __builtin_amdgcn_s_sleep(1);
    __builtin_amdgcn_fence(__ATOMIC_ACQUIRE, "agent");  // single inv
  }
  __syncthreads();
}

// 512-thread addressing core, 8 elems/thread (N=4096)
__device__ void addr_core8(int tid, float* loc, const float* sc, const float* __restrict__ wp,
                           float* wb, float* red) {
  const float g = sc[1], r = sc[2];
  const float s0 = sc[3], s1c = sc[4], s2 = sc[5];
  const int lane = tid & 63, wid = tid >> 6;  // wid 0..7
  __syncthreads();
  float mx = loc[0];
#pragma unroll
  for (int i = 1; i < 8; i++) mx = fmaxf(mx, loc[i]);
#pragma unroll
  for (int m = 1; m < 64; m <<= 1) mx = fmaxf(mx, __shfl_xor(mx, m, 64));
  if (lane == 0) red[wid] = mx;
  __syncthreads();
  mx = red[0];
#pragma unroll
  for (int k = 1; k < 8; k++) mx = fmaxf(mx, red[k]);
  float sum = 0.f;
#pragma unroll
  for (int i = 0; i < 8; i++) { loc[i] = exp2f((loc[i] - mx) * kLog2e); sum += loc[i]; }
#pragma unroll
  for (int m = 1; m < 64; m <<= 1) sum += __shfl_xor(sum, m, 64);
  __syncthreads();
  if (lane == 0) red[wid] = sum;
  __syncthreads();
  sum = red[0];
#pragma unroll
  for (int k = 1; k < 8; k++) sum += red[k];
  const float inv = 1.f / sum;
  const float omg = 1.f - g;
#pragma unroll
  for (int i = 0; i < 8; i++) {
    int n = tid + i * TPB;
    wb[n] = loc[i] * inv + omg * wp[n];
  }
  __syncthreads();
  float ssum = 0.f;
#pragma unroll
  for (int i = 0; i < 8; i++) {
    int n = tid + i * TPB;
    float sh = s0 * wb[(n + kN - 1) & (kN - 1)] + s1c * wb[n] + s2 * wb[(n + 1) & (kN - 1)];
    float y = (sh > 0.f) ? exp2f(r * log2f(sh)) : 0.f;
    loc[i] = y;
    ssum += y;
  }
#pragma unroll
  for (int m = 1; m < 64; m <<= 1) ssum += __shfl_xor(ssum, m, 64);
  __syncthreads();
  if (lane == 0) red[wid] = ssum;
  __syncthreads();
  ssum = red[0];
#pragma unroll
  for (int k = 1; k < 8; k++) ssum += red[k];
  const float invs = 1.f / (ssum + 1e-8f);
#pragma unroll
  for (int i = 0; i < 8; i++) loc[i] *= invs;
  __syncthreads();
}

__global__ __launch_bounds__(TPB, 2) void mega(Args P) {
  const int bid = blockIdx.x;
  const int tid = threadIdx.x;
  __shared__ SMem sm;

  // =============== Phase G: gates GEMM, 2-way k-split (256 blocks) ===============
  {
    const int khalf = bid >> 7;
    const int unit = bid & 127;
    const int b0 = (unit >> 5) * 16;
    const int j0 = (unit & 31) * 64;
    const int jg = tid & 63;
    const int bq2 = (tid >> 6) * 2;
    float acc0 = 0.f, acc1 = 0.f;
    for (int kc6 = 0; kc6 < 6; kc6++) {
      const int kc = khalf * 6 + kc6;
      const bool isx = kc < 4;
      const float* A = isx ? P.x : P.h_prev;
      const float* W = isx ? P.W_ih : P.W_hh;
      const int lda = isx ? kE : kH;
      const int k0 = (isx ? kc : (kc - 4)) * 64;
      __syncthreads();
      {  // A tile: 16 b x 64 k
        int bb = tid >> 5;
        int kk = (tid & 31) * 2;
        float2 v = *(const float2*)(A + (size_t)(b0 + bb) * lda + k0 + kk);
        sm.g.At[(kk + 0) * 20 + bb] = v.x;
        sm.g.At[(kk + 1) * 20 + bb] = v.y;
      }
#pragma unroll
      for (int i = 0; i < 2; i++) {  // W tile: 64 j x 64 k
        int idx = tid + i * 512;
        int jj = idx >> 4;
        int kk = (idx & 15) * 4;
        float4 w = *(const float4*)(W + (size_t)(j0 + jj) * lda + k0 + kk);
        sm.g.Wt[(kk + 0) * 65 + jj] = w.x; sm.g.Wt[(kk + 1) * 65 + jj] = w.y;
        sm.g.Wt[(kk + 2) * 65 + jj] = w.z; sm.g.Wt[(kk + 3) * 65 + jj] = w.w;
      }
      __syncthreads();
#pragma unroll 4
      for (int k = 0; k < 64; k++) {
        float2 av = *(const float2*)&sm.g.At[k * 20 + bq2];
        float wv = sm.g.Wt[k * 65 + jg];
        acc0 += av.x * wv; acc1 += av.y * wv;
      }
    }
    float* gd = khalf ? P.gates1 : P.gates0;
    gd[(size_t)(b0 + bq2 + 0) * kGates + j0 + jg] = acc0;
    gd[(size_t)(b0 + bq2 + 1) * kGates + j0 + jg] = acc1;
  }
  gsync(P.cnt, GRID * 1);

  // ====== Phase P: proj GEMM w/ fused h recompute, 2-way k-split (200 blocks) ======
  // 16 batches x 25 j-tiles x 2 k-halves: 4 bslices * 25 * 2 = 200 units (full B coverage)
  if (bid < 200) {
    const int kh = bid / 100;
    const int u = bid % 100;
    const int b0 = (u / 25) * 16;
    const int jt = u % 25;
    const int j0 = jt * 64;
    const int kbase = kh * 256;
    // recompute h for 16 batches, k in [kbase, kbase+256): 4096 vals, 8/thread
    for (int i = tid; i < 16 * 256; i += TPB) {
      int bb = i >> 8, kl = i & 255;
      int kk = kbase + kl;
      int b = b0 + bb;
      const float* g0 = P.gates0 + (size_t)b * kGates;
      const float* g1 = P.gates1 + (size_t)b * kGates;
      float i_ = g0[kk]        + g1[kk]        + P.b_ih[kk]        + P.b_hh[kk];
      float f_ = g0[512 + kk]  + g1[512 + kk]  + P.b_ih[512 + kk]  + P.b_hh[512 + kk];
      float gg = g0[1024 + kk] + g1[1024 + kk] + P.b_ih[1024 + kk] + P.b_hh[1024 + kk];
      float o_ = g0[1536 + kk] + g1[1536 + kk] + P.b_ih[1536 + kk] + P.b_hh[1536 + kk];
      float c = sigm_(f_) * P.c_prev[(size_t)b * kH + kk] + sigm_(i_) * tanhf(gg);
      float h = sigm_(o_) * tanhf(c);
      sm.p.hs[kl * 18 + bb] = h;
      if (jt == 0) P.cat[(size_t)b * kCatW + 3 * kM + kk] = h;
    }
    const int jg = tid & 63;
    const int bq2 = (tid >> 6) * 2;  // 2 batches per wave
    float acc0 = 0.f, acc1 = 0.f;
    for (int kc = 0; kc < 4; kc++) {
      const int k0 = kbase + kc * 64;
      const int kl0 = kc * 64;
      __syncthreads();
#pragma unroll
      for (int i = 0; i < 2; i++) {  // W tile: 64 j x 64 k
        int idx = tid + i * 512;
        int jj = idx >> 4;
        int kk = (idx & 15) * 4;
        int j = j0 + jj;
        float4 w = make_float4(0.f, 0.f, 0.f, 0.f);
        if (j < 1170)      w = *(const float4*)(P.write_W + (size_t)j * kH + k0 + kk);
        else if (j < 1572) w = *(const float4*)(P.read_W + (size_t)(j - 1170) * kH + k0 + kk);
        sm.p.Wt[(kk + 0) * 65 + jj] = w.x; sm.p.Wt[(kk + 1) * 65 + jj] = w.y;
        sm.p.Wt[(kk + 2) * 65 + jj] = w.z; sm.p.Wt[(kk + 3) * 65 + jj] = w.w;
      }
      __syncthreads();
#pragma unroll 4
      for (int k = 0; k < 64; k++) {
        float2 av = *(const float2*)&sm.p.hs[(kl0 + k) * 18 + bq2];
        float wv = sm.p.Wt[k * 65 + jg];
        acc0 += av.x * wv; acc1 += av.y * wv;
      }
    }
    float* pd = kh ? P.praw1 : P.praw0;
    if (j0 + jg < 1572) {
      pd[(size_t)(b0 + bq2 + 0) * kPRow + j0 + jg] = acc0;
      pd[(size_t)(b0 + bq2 + 1) * kPRow + j0 + jg] = acc1;
    }
  } else if (bid < 216) {  // out = bias
#pragma unroll
    for (int q = 0; q < 2; q++) {
      int i = (bid - 200) * 1024 + tid + q * 512;
      P.out[i] = P.out_b[i & (kO - 1)];
    }
  } else if (bid < 232) {  // cat[:, 0:384) = 0
#pragma unroll
    for (int q = 0; q < 3; q++) {
      int i = (bid - 216) * 1536 + tid + q * 512;
      P.cat[(size_t)(i / 384) * kCatW + (i % 384)] = 0.f;
    }
  }
  gsync(P.cnt, GRID * 2);

  // =============== Phase S: split params (6 heads in parallel) + sdots ===============
  if (bid < kB) {
    const int b = bid;
    const int m = tid & 127;
    const int hg = tid >> 7;  // 0..3
    const float* pr0 = P.praw0 + (size_t)b * kPRow;
    const float* pr1 = P.praw1 + (size_t)b * kPRow;
    {  // iter 0: heads {W0, W1, W2, R0}
      const bool isw = hg < 3;
      const int base = isw ? hg * 390 : 1170;
      const float* bias = isw ? (P.write_b + hg * 390) : P.read_b;
      const int slot = isw ? hg : 3;
      float kv = pr0[base + m] + pr1[base + m] + bias[m];
      if (isw) {
        P.kwb[((size_t)hg * kB + b) * kM + m] = kv;
        P.evb[((size_t)hg * kB + b) * kM + m] =
            sigm_(pr0[base + 134 + m] + pr1[base + 134 + m] + bias[134 + m]);
        P.avb[((size_t)hg * kB + b) * kM + m] =
            pr0[base + 262 + m] + pr1[base + 262 + m] + bias[262 + m];
      } else {
        P.krb[((size_t)0 * kB + b) * kM + m] = kv;
      }
      float sq = kv * kv;
#pragma unroll
      for (int mm = 1; mm < 64; mm <<= 1) sq += __shfl_xor(sq, mm, 64);
      if ((tid & 63) == 0) sm.s.nred[hg][m >> 6] = sq;
      __syncthreads();
      if (m == 0) {
        float* s = P.scal + ((size_t)slot * kB + b) * 8;
        s[0] = softplus_(pr0[base + 128] + pr1[base + 128] + bias[128]);
        s[1] = sigm_(pr0[base + 129] + pr1[base + 129] + bias[129]);
        s[2] = 1.f + softplus_(pr0[base + 133] + pr1[base + 133] + bias[133]);
        float x0 = pr0[base + 130] + pr1[base + 130] + bias[130];
        float x1 = pr0[base + 131] + pr1[base + 131] + bias[131];
        float x2 = pr0[base + 132] + pr1[base + 132] + bias[132];
        float mx = fmaxf(x0, fmaxf(x1, x2));
        float e0 = expf(x0 - mx), e1 = expf(x1 - mx), e2 = expf(x2 - mx);
        float si = 1.f / (e0 + e1 + e2);
        s[3] = e0 * si; s[4] = e1 * si; s[5] = e2 * si;
        s[6] = sqrtf(sm.s.nred[hg][0] + sm.s.nred[hg][1]);
      }
      __syncthreads();
    }
    {  // iter 1: heads {R1, R2} on hg 0,1 (hg 2,3 dummy)
      const int j = (hg < 2) ? hg + 1 : 2;
      const bool act = hg < 2;
      const int base = 1170 + j * 134;
      const float* bias = P.read_b + j * 134;
      const int slot = 3 + j;
      float kv = pr0[base + m] + pr1[base + m] + bias[m];
      if (act) P.krb[((size_t)j * kB + b) * kM + m] = kv;
      float sq = kv * kv;
#pragma unroll
      for (int mm = 1; mm < 64; mm <<= 1) sq += __shfl_xor(sq, mm, 64);
      if ((tid & 63) == 0) sm.s.nred[hg][m >> 6] = sq;
      __syncthreads();
      if (m == 0 && act) {
        float* s = P.scal + ((size_t)slot * kB + b) * 8;
        s[0] = softplus_(pr0[base + 128] + pr1[base + 128] + bias[128]);
        s[1] = sigm_(pr0[base + 129] + pr1[base + 129] + bias[129]);
        s[2] = 1.f + softplus_(pr0[base + 133] + pr1[base + 133] + bias[133]);
        float x0 = pr0[base + 130] + pr1[base + 130] + bias[130];
        float x1 = pr0[base + 131] + pr1[base + 131] + bias[131];
        float x2 = pr0[base + 132] + pr1[base + 132] + bias[132];
        float mx = fmaxf(x0, fmaxf(x1, x2));
        float e0 = expf(x0 - mx), e1 = expf(x1 - mx), e2 = expf(x2 - mx);
        float si = 1.f / (e0 + e1 + e2);
        s[3] = e0 * si; s[4] = e1 * si; s[5] = e2 * si;
        s[6] = sqrtf(sm.s.nred[hg][0] + sm.s.nred[hg][1]);
      }
      __syncthreads();
    }
    // sdots: {a0.kr0, a0.kw1, a0.a0, a2.kr2, a2.a2}
    if (tid < 64) {
      const float* a0v = P.avb + ((size_t)0 * kB + b) * kM;
      const float* a2v = P.avb + ((size_t)2 * kB + b) * kM;
      const float* u[5] = {a0v, a0v, a0v, a2v, a2v};
      const float* v[5] = {P.krb + ((size_t)0 * kB + b) * kM,
                           P.kwb + ((size_t)1 * kB + b) * kM,
                           a0v,
                           P.krb + ((size_t)2 * kB + b) * kM,
                           a2v};
#pragma unroll
      for (int d = 0; d < 5; d++) {
        float s = u[d][tid] * v[d][tid] + u[d][tid + 64] * v[d][tid + 64];
#pragma unroll
        for (int mm = 1; mm < 64; mm <<= 1) s += __shfl_xor(s, mm, 64);
        if (tid == 0) P.sdot[b * 8 + d] = s;
      }
    }
  }
  gsync(P.cnt, GRID * 3);

  // =============== Phase A: B0 moments (packed mA[n][12]) ===============
  {
    const int b = bid >> 2, chunk = bid & 3;
    const int lane = tid & 63, wv = tid >> 6, sub = lane >> 4, lm = lane & 15;
    const int m8 = lm * 8;
    float kw0r[8], kr0r[8], kw1r[8], a0r[8], e0r[8];
#pragma unroll
    for (int t = 0; t < 8; t++) {
      kw0r[t] = P.kwb[((size_t)0 * kB + b) * kM + m8 + t];
      kr0r[t] = P.krb[((size_t)0 * kB + b) * kM + m8 + t];
      kw1r[t] = P.kwb[((size_t)1 * kB + b) * kM + m8 + t];
      a0r[t]  = P.avb[((size_t)0 * kB + b) * kM + m8 + t];
      e0r[t]  = P.evb[((size_t)0 * kB + b) * kM + m8 + t];
    }
    const size_t bbase = (size_t)b * kN * kM;
    const size_t brow = (size_t)b * kN;
    const int row0 = chunk * 1024 + wv * 4 + sub;
    const float* base = P.bank + bbase + (size_t)row0 * kM + m8;
    float4 pA0 = *(const float4*)(base);
    float4 pA1 = *(const float4*)(base + 4);
    float4 pB0 = *(const float4*)(base + (size_t)32 * kM);
    float4 pB1 = *(const float4*)(base + (size_t)32 * kM + 4);
    for (int it = 0; it < 32; it++) {
      float v[8];
      if ((it & 1) == 0) {
        v[0]=pA0.x; v[1]=pA0.y; v[2]=pA0.z; v[3]=pA0.w; v[4]=pA1.x; v[5]=pA1.y; v[6]=pA1.z; v[7]=pA1.w;
        if (it + 2 < 32) {
          const float* np = base + (size_t)(it + 2) * 32 * kM;
          pA0 = *(const float4*)np; pA1 = *(const float4*)(np + 4);
        }
      } else {
        v[0]=pB0.x; v[1]=pB0.y; v[2]=pB0.z; v[3]=pB0.w; v[4]=pB1.x; v[5]=pB1.y; v[6]=pB1.z; v[7]=pB1.w;
        if (it + 2 < 32) {
          const float* np = base + (size_t)(it + 2) * 32 * kM;
          pB0 = *(const float4*)np; pB1 = *(const float4*)(np + 4);
        }
      }
      const int row = row0 + it * 32;
      float s[10] = {};
#pragma unroll
      for (int t = 0; t < 8; t++) {
        float be = v[t] * e0r[t];
        s[0] += v[t] * kw0r[t];
        s[1] += v[t] * v[t];
        s[2] += v[t] * kr0r[t];
        s[3] += be * kr0r[t];
        s[4] += v[t] * kw1r[t];
        s[5] += be * kw1r[t];
        s[6] += be * v[t];
        s[7] += be * be;
        s[8] += v[t] * a0r[t];
        s[9] += be * a0r[t];
      }
#pragma unroll
      for (int m = 1; m < 16; m <<= 1)
#pragma unroll
        for (int k = 0; k < 10; k++) s[k] += __shfl_xor(s[k], m, 64);
      if (lm == 0) {
        float4* dst = (float4*)(P.mA + (size_t)(brow + row) * 12);
        dst[0] = make_float4(s[0], s[1], s[2], s[3]);
        dst[1] = make_float4(s[4], s[5], s[6], s[7]);
        dst[2] = make_float4(s[8], s[9], 0.f, 0.f);
      }
    }
  }
  gsync(P.cnt, GRID * 4);

  // ====== Phase A12 (128 blocks, role-split): role0: w0 -> wr0; role1: w0(dup) -> w1 ======
  if (bid < 2 * kB) {
    const int b = bid & 63, role = bid >> 6;
    const size_t brow = (size_t)b * kN;
    float loc[8], w0r[8];
    {  // write head 0 on B0 (both roles compute; role0 stores)
      const float* sc = P.scal + ((size_t)0 * kB + b) * 8;
      const float beta = sc[0], kn = sc[6];
#pragma unroll
      for (int i = 0; i < 8; i++) {
        const float* mp = P.mA + (size_t)(brow + tid + i * TPB) * 12;
        float4 q0 = *(const float4*)mp;
        loc[i] = beta * q0.x / fmaxf(sqrtf(fmaxf(q0.y, 0.f)) * kn, 1e-8f);
      }
      addr_core8(tid, loc, sc, P.write_w_prev + brow, sm.a.wb, sm.a.red);
#pragma unroll
      for (int i = 0; i < 8; i++) {
        w0r[i] = loc[i];
        if (role == 0) P.wp0[brow + tid + i * TPB] = loc[i];
      }
    }
    if (role == 0) {  // read head 0 on B1 (expanded)
      const float* sc = P.scal + ((size_t)3 * kB + b) * 8;
      const float beta = sc[0], kn = sc[6];
      const float sa0kr0 = P.sdot[b * 8 + 0], sa0a0 = P.sdot[b * 8 + 2];
#pragma unroll
      for (int i = 0; i < 8; i++) {
        const float* mp = P.mA + (size_t)(brow + tid + i * TPB) * 12;
        float4 q0 = *(const float4*)mp;
        float4 q1 = *(const float4*)(mp + 4);
        float4 q2 = *(const float4*)(mp + 8);
        float w0 = w0r[i], w0q = w0 * w0;
        float q1v = q0.y - 2.f * w0 * q1.z + w0q * q1.w + 2.f * w0 * q2.x
                  - 2.f * w0q * q2.y + w0q * sa0a0;
        float d = q0.z - w0 * q0.w + w0 * sa0kr0;
        loc[i] = beta * d / fmaxf(sqrtf(fmaxf(q1v, 0.f)) * kn, 1e-8f);
      }
      addr_core8(tid, loc, sc, P.read_w_prev + brow, sm.a.wb, sm.a.red);
#pragma unroll
      for (int i = 0; i < 8; i++) P.wp2[brow + tid + i * TPB] = loc[i];
    } else {  // write head 1 on B1 (expanded; recompute q1v locally)
      const float* sc = P.scal + ((size_t)1 * kB + b) * 8;
      const float beta = sc[0], kn = sc[6];
      const float sa0kw1 = P.sdot[b * 8 + 1], sa0a0 = P.sdot[b * 8 + 2];
#pragma unroll
      for (int i = 0; i < 8; i++) {
        const float* mp = P.mA + (size_t)(brow + tid + i * TPB) * 12;
        float4 q0 = *(const float4*)mp;
        float4 q1 = *(const float4*)(mp + 4);
        float4 q2 = *(const float4*)(mp + 8);
        float w0 = w0r[i], w0q = w0 * w0;
        float q1v = q0.y - 2.f * w0 * q1.z + w0q * q1.w + 2.f * w0 * q2.x
                  - 2.f * w0q * q2.y + w0q * sa0a0;
        float d = q1.x - w0 * q1.y + w0 * sa0kw1;
        loc[i] = beta * d / fmaxf(sqrtf(fmaxf(q1v, 0.f)) * kn, 1e-8f);
      }
      addr_core8(tid, loc, sc, P.write_w_prev + (size_t)kWN + brow, sm.a.wb, sm.a.red);
#pragma unroll
      for (int i = 0; i < 8; i++) P.wp1[brow + tid + i * TPB] = loc[i];
    }
  }
  gsync(P.cnt, GRID * 5);

  // =============== Phase B: chain(w0,w1), read0, B2 moments (mB[n][12]) ===============
  {
    const int b = bid >> 2, chunk = bid & 3;
    const int lane = tid & 63, wv = tid >> 6, sub = lane >> 4, lm = lane & 15;
    const int m8 = lm * 8;
    float e0r[8], a0r[8], e1r[8], a1r[8], kr1r[8], kw2r[8], kr2r[8], e2r[8], a2r[8];
#pragma unroll
    for (int t = 0; t < 8; t++) {
      e0r[t]  = P.evb[((size_t)0 * kB + b) * kM + m8 + t];
      a0r[t]  = P.avb[((size_t)0 * kB + b) * kM + m8 + t];
      e1r[t]  = P.evb[((size_t)1 * kB + b) * kM + m8 + t];
      a1r[t]  = P.avb[((size_t)1 * kB + b) * kM + m8 + t];
      kr1r[t] = P.krb[((size_t)1 * kB + b) * kM + m8 + t];
      kw2r[t] = P.kwb[((size_t)2 * kB + b) * kM + m8 + t];
      kr2r[t] = P.krb[((size_t)2 * kB + b) * kM + m8 + t];
      e2r[t]  = P.evb[((size_t)2 * kB + b) * kM + m8 + t];
      a2r[t]  = P.avb[((size_t)2 * kB + b) * kM + m8 + t];
    }
    float racc[8] = {};
    if (tid < kM) sm.r.rl[tid] = 0.f;
    const size_t bbase = (size_t)b * kN * kM;
    const size_t brow = (size_t)b * kN;
    const int row0 = chunk * 1024 + wv * 4 + sub;
    const float* base = P.bank + bbase + (size_t)row0 * kM + m8;
    const size_t wrow = brow + row0;
    float4 pA0 = *(const float4*)(base);
    float4 pA1 = *(const float4*)(base + 4);
    float4 pB0 = *(const float4*)(base + (size_t)32 * kM);
    float4 pB1 = *(const float4*)(base + (size_t)32 * kM + 4);
    float w0A = P.wp0[wrow], w1A = P.wp1[wrow], r0A = P.wp2[wrow];
    float w0B = P.wp0[wrow + 32], w1B = P.wp1[wrow + 32], r0B = P.wp2[wrow + 32];
    for (int it = 0; it < 32; it++) {
      float v[8];
      float w0, w1, wr0;
      if ((it & 1) == 0) {
        v[0]=pA0.x; v[1]=pA0.y; v[2]=pA0.z; v[3]=pA0.w; v[4]=pA1.x; v[5]=pA1.y; v[6]=pA1.z; v[7]=pA1.w;
        w0 = w0A; w1 = w1A; wr0 = r0A;
        if (it + 2 < 32) {
          const float* np = base + (size_t)(it + 2) * 32 * kM;
          pA0 = *(const float4*)np; pA1 = *(const float4*)(np + 4);
          size_t wn = wrow + (size_t)(it + 2) * 32;
          w0A = P.wp0[wn]; w1A = P.wp1[wn]; r0A = P.wp2[wn];
        }
      } else {
        v[0]=pB0.x; v[1]=pB0.y; v[2]=pB0.z; v[3]=pB0.w; v[4]=pB1.x; v[5]=pB1.y; v[6]=pB1.z; v[7]=pB1.w;
        w0 = w0B; w1 = w1B; wr0 = r0B;
        if (it + 2 < 32) {
          const float* np = base + (size_t)(it + 2) * 32 * kM;
          pB0 = *(const float4*)np; pB1 = *(const float4*)(np + 4);
          size_t wn = wrow + (size_t)(it + 2) * 32;
          w0B = P.wp0[wn]; w1B = P.wp1[wn]; r0B = P.wp2[wn];
        }
      }
      const int row = row0 + it * 32;
#pragma unroll
      for (int t = 0; t < 8; t++) {
        v[t] += w0 * (a0r[t] - e0r[t] * v[t]);  // -> B1
        racc[t] += wr0 * v[t];                   // read0 from B1
        v[t] += w1 * (a1r[t] - e1r[t] * v[t]);  // -> B2
      }
      float s[9] = {};
#pragma unroll
      for (int t = 0; t < 8; t++) {
        float ve = v[t] * e2r[t];
        s[0] += v[t] * kr1r[t];
        s[1] += v[t] * kw2r[t];
        s[2] += v[t] * v[t];
        s[3] += v[t] * kr2r[t];
        s[4] += ve * kr2r[t];
        s[5] += ve * v[t];
        s[6] += ve * ve;
        s[7] += v[t] * a2r[t];
        s[8] += ve * a2r[t];
      }
#pragma unroll
      for (int m = 1; m < 16; m <<= 1)
#pragma unroll
        for (int k = 0; k < 9; k++) s[k] += __shfl_xor(s[k], m, 64);
      if (lm == 0) {
        float4* dst = (float4*)(P.mB + (size_t)(brow + row) * 12);
        dst[0] = make_float4(s[0], s[1], s[2], s[3]);
        dst[1] = make_float4(s[4], s[5], s[6], s[7]);
        dst[2] = make_float4(s[8], 0.f, 0.f, 0.f);
      }
    }
    __syncthreads();
#pragma unroll
    for (int t = 0; t < 8; t++) {
      racc[t] += __shfl_xor(racc[t], 16, 64);
      racc[t] += __shfl_xor(racc[t], 32, 64);
    }
    if (sub == 0) {
#pragma unroll
      for (int t = 0; t < 8; t++) atomicAdd(&sm.r.rl[m8 + t], racc[t]);
    }
    __syncthreads();
    if (tid < kM) atomicAdd(&P.cat[(size_t)b * kCatW + tid], sm.r.rl[tid]);
  }
  gsync(P.cnt, GRID * 6);

  // ====== Phase A34 (128 blocks, role-split): role0: w2 -> wr2; role1: wr1 ======
  if (bid < 2 * kB) {
    const int b = bid & 63, role = bid >> 6;
    const size_t brow = (size_t)b * kN;
    float loc[8];
    if (role == 0) {
      float w2r[8];
      {  // write head 2 on B2
        const float* sc = P.scal + ((size_t)2 * kB + b) * 8;
        const float beta = sc[0], kn = sc[6];
#pragma unroll
        for (int i = 0; i < 8; i++) {
          const float* mp = P.mB + (size_t)(brow + tid + i * TPB) * 12;
          float4 q0 = *(const float4*)mp;
          loc[i] = beta * q0.y / fmaxf(sqrtf(fmaxf(q0.z, 0.f)) * kn, 1e-8f);
        }
        addr_core8(tid, loc, sc, P.write_w_prev + (size_t)2 * kWN + brow, sm.a.wb, sm.a.red);
#pragma unroll
        for (int i = 0; i < 8; i++) {
          P.wp3[brow + tid + i * TPB] = loc[i];
          w2r[i] = loc[i];
        }
      }
      {  // read head 2 on B3 (expanded)
        const float* sc = P.scal + ((size_t)5 * kB + b) * 8;
        const float beta = sc[0], kn = sc[6];
        const float sa2kr2 = P.sdot[b * 8 + 3], sa2a2 = P.sdot[b * 8 + 4];
#pragma unroll
        for (int i = 0; i < 8; i++) {
          const float* mp = P.mB + (size_t)(brow + tid + i * TPB) * 12;
          float4 q0 = *(const float4*)mp;
          float4 q1 = *(const float4*)(mp + 4);
          float4 q2 = *(const float4*)(mp + 8);
          float w2 = w2r[i], w2q = w2 * w2;
          float q3 = q0.z - 2.f * w2 * q1.y + w2q * q1.z + 2.f * w2 * q1.w
                   - 2.f * w2q * q2.x + w2q * sa2a2;
          float d = q0.w - w2 * q1.x + w2 * sa2kr2;
          loc[i] = beta * d / fmaxf(sqrtf(fmaxf(q3, 0.f)) * kn, 1e-8f);
        }
        addr_core8(tid, loc, sc, P.read_w_prev + (size_t)2 * kWN + brow, sm.a.wb, sm.a.red);
#pragma unroll
        for (int i = 0; i < 8; i++) P.wp5[brow + tid + i * TPB] = loc[i];
      }
    } else {
      {  // read head 1 on B2 (independent of w2)
        const float* sc = P.scal + ((size_t)4 * kB + b) * 8;
        const float beta = sc[0], kn = sc[6];
#pragma unroll
        for (int i = 0; i < 8; i++) {
          const float* mp = P.mB + (size_t)(brow + tid + i * TPB) * 12;
          float4 q0 = *(const float4*)mp;
          loc[i] = beta * q0.x / fmaxf(sqrtf(fmaxf(q0.z, 0.f)) * kn, 1e-8f);
        }
        addr_core8(tid, loc, sc, P.read_w_prev + (size_t)kWN + brow, sm.a.wb, sm.a.red);
#pragma unroll
        for (int i = 0; i < 8; i++) P.wp4[brow + tid + i * TPB] = loc[i];
      }
    }
  }
  gsync(P.cnt, GRID * 7);

  // =============== Phase C: chain(w0,w1,w2), read1 from B2, read2 from B3 ===============
  {
    const int b = bid >> 2, chunk = bid & 3;
    const int lane = tid & 63, wv = tid >> 6, sub = lane >> 4, lm = lane & 15;
    const int m8 = lm * 8;
    float e_r[3][8], a_r[3][8];
#pragma unroll
    for (int j = 0; j < 3; j++)
#pragma unroll
      for (int t = 0; t < 8; t++) {
        e_r[j][t] = P.evb[((size_t)j * kB + b) * kM + m8 + t];
        a_r[j][t] = P.avb[((size_t)j * kB + b) * kM + m8 + t];
      }
    float racc1[8] = {}, racc2[8] = {};
    if (tid < kM) { sm.r.rl[tid] = 0.f; sm.r.rl[kM + tid] = 0.f; }
    const size_t bbase = (size_t)b * kN * kM;
    const size_t brow = (size_t)b * kN;
    const int row0 = chunk * 1024 + wv * 4 + sub;
    const float* base = P.bank + bbase + (size_t)row0 * kM + m8;
    const size_t wrow = brow + row0;
    float4 pA0 = *(const float4*)(base);
    float4 pA1 = *(const float4*)(base + 4);
    float4 pB0 = *(const float4*)(base + (size_t)32 * kM);
    float4 pB1 = *(const float4*)(base + (size_t)32 * kM + 4);
    float c0A = P.wp0[wrow], c1A = P.wp1[wrow], c2A = P.wp3[wrow], c3A = P.wp4[wrow], c4A = P.wp5[wrow];
    float c0B = P.wp0[wrow + 32], c1B = P.wp1[wrow + 32], c2B = P.wp3[wrow + 32],
          c3B = P.wp4[wrow + 32], c4B = P.wp5[wrow + 32];
    for (int it = 0; it < 32; it++) {
      float v[8];
      float w0, w1, w2, wr1, wr2;
      if ((it & 1) == 0) {
        v[0]=pA0.x; v[1]=pA0.y; v[2]=pA0.z; v[3]=pA0.w; v[4]=pA1.x; v[5]=pA1.y; v[6]=pA1.z; v[7]=pA1.w;
        w0 = c0A; w1 = c1A; w2 = c2A; wr1 = c3A; wr2 = c4A;
        if (it + 2 < 32) {
          const float* np = base + (size_t)(it + 2) * 32 * kM;
          pA0 = *(const float4*)np; pA1 = *(const float4*)(np + 4);
          size_t wn = wrow + (size_t)(it + 2) * 32;
          c0A = P.wp0[wn]; c1A = P.wp1[wn]; c2A = P.wp3[wn]; c3A = P.wp4[wn]; c4A = P.wp5[wn];
        }
      } else {
        v[0]=pB0.x; v[1]=pB0.y; v[2]=pB0.z; v[3]=pB0.w; v[4]=pB1.x; v[5]=pB1.y; v[6]=pB1.z; v[7]=pB1.w;
        w0 = c0B; w1 = c1B; w2 = c2B; wr1 = c3B; wr2 = c4B;
        if (it + 2 < 32) {
          const float* np = base + (size_t)(it + 2) * 32 * kM;
          pB0 = *(const float4*)np; pB1 = *(const float4*)(np + 4);
          size_t wn = wrow + (size_t)(it + 2) * 32;
          c0B = P.wp0[wn]; c1B = P.wp1[wn]; c2B = P.wp3[wn]; c3B = P.wp4[wn]; c4B = P.wp5[wn];
        }
      }
#pragma unroll
      for (int t = 0; t < 8; t++) {
        v[t] += w0 * (a_r[0][t] - e_r[0][t] * v[t]);  // B1
        v[t] += w1 * (a_r[1][t] - e_r[1][t] * v[t]);  // B2
        racc1[t] += wr1 * v[t];
        v[t] += w2 * (a_r[2][t] - e_r[2][t] * v[t]);  // B3
        racc2[t] += wr2 * v[t];
      }
    }
    __syncthreads();
#pragma unroll
    for (int t = 0; t < 8; t++) {
      racc1[t] += __shfl_xor(racc1[t], 16, 64);
      racc1[t] += __shfl_xor(racc1[t], 32, 64);
      racc2[t] += __shfl_xor(racc2[t], 16, 64);
      racc2[t] += __shfl_xor(racc2[t], 32, 64);
    }
    if (sub == 0) {
#pragma unroll
      for (int t = 0; t < 8; t++) {
        atomicAdd(&sm.r.rl[m8 + t], racc1[t]);
        atomicAdd(&sm.r.rl[kM + m8 + t], racc2[t]);
      }
    }
    __syncthreads();
    if (tid < kM) {
      atomicAdd(&P.cat[(size_t)b * kCatW + kM + tid], sm.r.rl[tid]);
      atomicAdd(&P.cat[(size_t)b * kCatW + 2 * kM + tid], sm.r.rl[kM + tid]);
    }
  }
  gsync(P.cnt, GRID * 8);

  // =============== Phase O: out GEMM (56 blocks, split-k atomic) ===============
  if (bid < 56) {
    const int jt = bid & 3, kt = bid >> 2;  // kt 0..13
    const int j0 = jt * 64, k0 = kt * 64;
    {
      int bb = tid >> 3;
      int kk = (tid & 7) * 8;
      float4 v0 = *(const float4*)(P.cat + (size_t)bb * kCatW + k0 + kk);
      float4 v1 = *(const float4*)(P.cat + (size_t)bb * kCatW + k0 + kk + 4);
      sm.o.As[(kk + 0) * 72 + bb] = v0.x; sm.o.As[(kk + 1) * 72 + bb] = v0.y;
      sm.o.As[(kk + 2) * 72 + bb] = v0.z; sm.o.As[(kk + 3) * 72 + bb] = v0.w;
      sm.o.As[(kk + 4) * 72 + bb] = v1.x; sm.o.As[(kk + 5) * 72 + bb] = v1.y;
      sm.o.As[(kk + 6) * 72 + bb] = v1.z; sm.o.As[(kk + 7) * 72 + bb] = v1.w;
      float4 w0_ = *(const float4*)(P.out_W + (size_t)(j0 + bb) * kCatW + k0 + kk);
      float4 w1_ = *(const float4*)(P.out_W + (size_t)(j0 + bb) * kCatW + k0 + kk + 4);
      sm.o.Ws[(kk + 0) * 72 + bb] = w0_.x; sm.o.Ws[(kk + 1) * 72 + bb] = w0_.y;
      sm.o.Ws[(kk + 2) * 72 + bb] = w0_.z; sm.o.Ws[(kk + 3) * 72 + bb] = w0_.w;
      sm.o.Ws[(kk + 4) * 72 + bb] = w1_.x; sm.o.Ws[(kk + 5) * 72 + bb] = w1_.y;
      sm.o.Ws[(kk + 6) * 72 + bb] = w1_.z; sm.o.Ws[(kk + 7) * 72 + bb] = w1_.w;
    }
    __syncthreads();
    const int b0 = (tid & 15) * 4;
    const int jq = (tid >> 4) * 2;
    float acc[4][2] = {};
#pragma unroll 2
    for (int k = 0; k < 64; k++) {
      float4 av = *(const float4*)&sm.o.As[k * 72 + b0];
      float2 wv = *(const float2*)&sm.o.Ws[k * 72 + jq];
      acc[0][0] += av.x * wv.x; acc[0][1] += av.x * wv.y;
      acc[1][0] += av.y * wv.x; acc[1][1] += av.y * wv.y;
      acc[2][0] += av.z * wv.x; acc[2][1] += av.z * wv.y;
      acc[3][0] += av.w * wv.x; acc[3][1] += av.w * wv.y;
    }
#pragma unroll
    for (int ii = 0; ii < 4; ii++) {
      atomicAdd(&P.out[(size_t)(b0 + ii) * kO + j0 + jq + 0], acc[ii][0]);
      atomicAdd(&P.out[(size_t)(b0 + ii) * kO + j0 + jq + 1], acc[ii][1]);
    }
  }
}

}  // namespace

extern "C" void kernel_launch(void* const* d_in, const int* in_sizes, int n_in,
                              void* d_out, int out_size, void* d_ws, size_t ws_size,
                              hipStream_t stream) {
  Args A_;
  A_.x            = (const float*)d_in[0];
  A_.h_prev       = (const float*)d_in[1];
  A_.c_prev       = (const float*)d_in[2];
  A_.bank         = (const float*)d_in[3];
  A_.read_w_prev  = (const float*)d_in[4];
  A_.write_w_prev = (const float*)d_in[5];
  A_.W_ih         = (const float*)d_in[6];
  A_.W_hh         = (const float*)d_in[7];
  A_.b_ih         = (const float*)d_in[8];
  A_.b_hh         = (const float*)d_in[9];
  A_.read_W       = (const float*)d_in[10];
  A_.read_b       = (const float*)d_in[11];
  A_.write_W      = (const float*)d_in[12];
  A_.write_b      = (const float*)d_in[13];
  A_.out_W        = (const float*)d_in[14];
  A_.out_b        = (const float*)d_in[15];
  A_.out = (float*)d_out;

  float* ws = (float*)d_ws;
  A_.cnt = (unsigned*)d_ws;  // first 256 B: barrier counter
  float* p = ws + 64;
  A_.gates0 = p; p += (size_t)kB * kGates;
  A_.gates1 = p; p += (size_t)kB * kGates;
  A_.praw0  = p; p += (size_t)kB * kPRow;
  A_.praw1  = p; p += (size_t)kB * kPRow;
  A_.cat    = p; p += (size_t)kB * kCatW;
  A_.kwb    = p; p += (size_t)3 * kB * kM;
  A_.krb    = p; p += (size_t)3 * kB * kM;
  A_.evb    = p; p += (size_t)3 * kB * kM;
  A_.avb    = p; p += (size_t)3 * kB * kM;
  A_.scal   = p; p += (size_t)6 * kB * 8;
  A_.sdot   = p; p += (size_t)kB * 8;
  A_.wp0    = p; p += (size_t)kWN;
  A_.wp1    = p; p += (size_t)kWN;
  A_.wp2    = p; p += (size_t)kWN;
  A_.wp3    = p; p += (size_t)kWN;
  A_.wp4    = p; p += (size_t)kWN;
  A_.wp5    = p; p += (size_t)kWN;
  A_.mA     = p; p += (size_t)kWN * 12;
  A_.mB     = p; p += (size_t)kWN * 12;

  hipMemsetAsync(d_ws, 0, 256, stream);
  mega<<<dim3(GRID), dim3(TPB), 0, stream>>>(A_);

  (void)in_sizes; (void)n_in; (void)out_size; (void)ws_size;
}

// Round 4
// 430.759 us; speedup vs baseline: 1.7045x; 1.1397x over previous
//
#include <hip/hip_runtime.h>
#include <math.h>

namespace {

constexpr int kB = 64;
constexpr int kN = 4096;
constexpr int kM = 128;
constexpr int kH = 512;
constexpr int kE = 256;
constexpr int kO = 256;
constexpr int kGates = 4 * kH;      // 2048
constexpr int kCatW = 3 * kM + kH;  // 896
constexpr int kPRow = 1600;         // padded 1572
constexpr int kWN = kB * kN;
constexpr int GRID = 256;
constexpr int TPB = 512;
constexpr float kLog2e = 1.4426950408889634f;

__device__ __forceinline__ float sigm_(float x) { return 1.f / (1.f + expf(-x)); }
__device__ __forceinline__ float softplus_(float x) { return x > 20.f ? x : log1pf(expf(x)); }

struct Args {
  const float *x, *h_prev, *c_prev, *bank, *read_w_prev, *write_w_prev;
  const float *W_ih, *W_hh, *b_ih, *b_hh, *read_W, *read_b, *write_W, *write_b, *out_W, *out_b;
  float *out;
  float *gates0, *gates1, *praw0, *praw1, *cat;
  float *kwb, *krb, *evb, *avb, *scal, *sdot;
  float *wp0, *wp1, *wp2, *wp3, *wp4, *wp5;
  float *mA, *mB;
  unsigned *gcnt;   // global barrier counter
  unsigned *bcnt;   // per-batch counters, stride 32 u32 (128 B) each
};

union SMem {
  struct { float At[64 * 20]; float Wt[64 * 65]; } g;   // gates tiles
  struct { float hs[256 * 18]; float Wt[64 * 65]; } p;  // proj: 16-batch h-slice + W tile
  struct { float wb[kN]; float red[8]; } a;             // addressing
  struct { float nred[4][2]; } s;                       // split norms
  struct { float rl[2 * kM]; } r;                       // passB/C read reduce
};

// Barrier primitive. CRITICAL: poll with RELAXED loads (no per-iteration cache
// invalidation); one release fence (writeback) before arrival, one acquire
// fence (inv) after exit. (Round-1 evidence: acquire-polling = L2 inv storm,
// 590us at 7.5% VALUBusy.)
__device__ __forceinline__ void barrier_on(unsigned* c, unsigned target) {
  __syncthreads();
  if (threadIdx.x == 0) {
    __builtin_amdgcn_fence(__ATOMIC_RELEASE, "agent");
    __hip_atomic_fetch_add(c, 1u, __ATOMIC_RELAXED, __HIP_MEMORY_SCOPE_AGENT);
    while (__hip_atomic_load(c, __ATOMIC_RELAXED, __HIP_MEMORY_SCOPE_AGENT) < target)
      __builtin_amdgcn_s_sleep(1);
    __builtin_amdgcn_fence(__ATOMIC_ACQUIRE, "agent");
  }
  __syncthreads();
}

// 512-thread addressing core, 8 elems/thread (N=4096)
__device__ void addr_core8(int tid, float* loc, const float* sc, const float* __restrict__ wp,
                           float* wb, float* red) {
  const float g = sc[1], r = sc[2];
  const float s0 = sc[3], s1c = sc[4], s2 = sc[5];
  const int lane = tid & 63, wid = tid >> 6;  // wid 0..7
  __syncthreads();
  float mx = loc[0];
#pragma unroll
  for (int i = 1; i < 8; i++) mx = fmaxf(mx, loc[i]);
#pragma unroll
  for (int m = 1; m < 64; m <<= 1) mx = fmaxf(mx, __shfl_xor(mx, m, 64));
  if (lane == 0) red[wid] = mx;
  __syncthreads();
  mx = red[0];
#pragma unroll
  for (int k = 1; k < 8; k++) mx = fmaxf(mx, red[k]);
  float sum = 0.f;
#pragma unroll
  for (int i = 0; i < 8; i++) { loc[i] = exp2f((loc[i] - mx) * kLog2e); sum += loc[i]; }
#pragma unroll
  for (int m = 1; m < 64; m <<= 1) sum += __shfl_xor(sum, m, 64);
  __syncthreads();
  if (lane == 0) red[wid] = sum;
  __syncthreads();
  sum = red[0];
#pragma unroll
  for (int k = 1; k < 8; k++) sum += red[k];
  const float inv = 1.f / sum;
  const float omg = 1.f - g;
#pragma unroll
  for (int i = 0; i < 8; i++) {
    int n = tid + i * TPB;
    wb[n] = loc[i] * inv + omg * wp[n];
  }
  __syncthreads();
  float ssum = 0.f;
#pragma unroll
  for (int i = 0; i < 8; i++) {
    int n = tid + i * TPB;
    float sh = s0 * wb[(n + kN - 1) & (kN - 1)] + s1c * wb[n] + s2 * wb[(n + 1) & (kN - 1)];
    float y = (sh > 0.f) ? exp2f(r * log2f(sh)) : 0.f;
    loc[i] = y;
    ssum += y;
  }
#pragma unroll
  for (int m = 1; m < 64; m <<= 1) ssum += __shfl_xor(ssum, m, 64);
  __syncthreads();
  if (lane == 0) red[wid] = ssum;
  __syncthreads();
  ssum = red[0];
#pragma unroll
  for (int k = 1; k < 8; k++) ssum += red[k];
  const float invs = 1.f / (ssum + 1e-8f);
#pragma unroll
  for (int i = 0; i < 8; i++) loc[i] *= invs;
  __syncthreads();
}

__global__ __launch_bounds__(TPB, 2) void mega(Args P) {
  const int bid = blockIdx.x;
  const int tid = threadIdx.x;
  __shared__ SMem sm;

  // Per-batch group mapping: batch bb = bid & 63, member sub = bid >> 6.
  // Group {b, b+64, b+128, b+192} shares bid%8 -> same XCD (L2 locality).
  const int bb_ = bid & 63;
  const int sub_ = bid >> 6;
  unsigned* bc = P.bcnt + bb_ * 32;

  // =============== Phase G: gates GEMM, 2-way k-split (256 blocks) ===============
  {
    const int khalf = bid >> 7;
    const int unit = bid & 127;
    const int b0 = (unit >> 5) * 16;
    const int j0 = (unit & 31) * 64;
    const int jg = tid & 63;
    const int bq2 = (tid >> 6) * 2;
    float acc0 = 0.f, acc1 = 0.f;
    for (int kc6 = 0; kc6 < 6; kc6++) {
      const int kc = khalf * 6 + kc6;
      const bool isx = kc < 4;
      const float* A = isx ? P.x : P.h_prev;
      const float* W = isx ? P.W_ih : P.W_hh;
      const int lda = isx ? kE : kH;
      const int k0 = (isx ? kc : (kc - 4)) * 64;
      __syncthreads();
      {  // A tile: 16 b x 64 k
        int bb = tid >> 5;
        int kk = (tid & 31) * 2;
        float2 v = *(const float2*)(A + (size_t)(b0 + bb) * lda + k0 + kk);
        sm.g.At[(kk + 0) * 20 + bb] = v.x;
        sm.g.At[(kk + 1) * 20 + bb] = v.y;
      }
#pragma unroll
      for (int i = 0; i < 2; i++) {  // W tile: 64 j x 64 k
        int idx = tid + i * 512;
        int jj = idx >> 4;
        int kk = (idx & 15) * 4;
        float4 w = *(const float4*)(W + (size_t)(j0 + jj) * lda + k0 + kk);
        sm.g.Wt[(kk + 0) * 65 + jj] = w.x; sm.g.Wt[(kk + 1) * 65 + jj] = w.y;
        sm.g.Wt[(kk + 2) * 65 + jj] = w.z; sm.g.Wt[(kk + 3) * 65 + jj] = w.w;
      }
      __syncthreads();
#pragma unroll 4
      for (int k = 0; k < 64; k++) {
        float2 av = *(const float2*)&sm.g.At[k * 20 + bq2];
        float wv = sm.g.Wt[k * 65 + jg];
        acc0 += av.x * wv; acc1 += av.y * wv;
      }
    }
    float* gd = khalf ? P.gates1 : P.gates0;
    gd[(size_t)(b0 + bq2 + 0) * kGates + j0 + jg] = acc0;
    gd[(size_t)(b0 + bq2 + 1) * kGates + j0 + jg] = acc1;
  }
  barrier_on(P.gcnt, GRID * 1);

  // ====== Phase P: proj GEMM w/ fused h recompute, 2-way k-split (200 blocks) ======
  if (bid < 200) {
    const int kh = bid / 100;
    const int u = bid % 100;
    const int b0 = (u / 25) * 16;
    const int jt = u % 25;
    const int j0 = jt * 64;
    const int kbase = kh * 256;
    for (int i = tid; i < 16 * 256; i += TPB) {
      int bb = i >> 8, kl = i & 255;
      int kk = kbase + kl;
      int b = b0 + bb;
      const float* g0 = P.gates0 + (size_t)b * kGates;
      const float* g1 = P.gates1 + (size_t)b * kGates;
      float i_ = g0[kk]        + g1[kk]        + P.b_ih[kk]        + P.b_hh[kk];
      float f_ = g0[512 + kk]  + g1[512 + kk]  + P.b_ih[512 + kk]  + P.b_hh[512 + kk];
      float gg = g0[1024 + kk] + g1[1024 + kk] + P.b_ih[1024 + kk] + P.b_hh[1024 + kk];
      float o_ = g0[1536 + kk] + g1[1536 + kk] + P.b_ih[1536 + kk] + P.b_hh[1536 + kk];
      float c = sigm_(f_) * P.c_prev[(size_t)b * kH + kk] + sigm_(i_) * tanhf(gg);
      float h = sigm_(o_) * tanhf(c);
      sm.p.hs[kl * 18 + bb] = h;
      if (jt == 0) P.cat[(size_t)b * kCatW + 3 * kM + kk] = h;
    }
    const int jg = tid & 63;
    const int bq2 = (tid >> 6) * 2;
    float acc0 = 0.f, acc1 = 0.f;
    for (int kc = 0; kc < 4; kc++) {
      const int k0 = kbase + kc * 64;
      const int kl0 = kc * 64;
      __syncthreads();
#pragma unroll
      for (int i = 0; i < 2; i++) {
        int idx = tid + i * 512;
        int jj = idx >> 4;
        int kk = (idx & 15) * 4;
        int j = j0 + jj;
        float4 w = make_float4(0.f, 0.f, 0.f, 0.f);
        if (j < 1170)      w = *(const float4*)(P.write_W + (size_t)j * kH + k0 + kk);
        else if (j < 1572) w = *(const float4*)(P.read_W + (size_t)(j - 1170) * kH + k0 + kk);
        sm.p.Wt[(kk + 0) * 65 + jj] = w.x; sm.p.Wt[(kk + 1) * 65 + jj] = w.y;
        sm.p.Wt[(kk + 2) * 65 + jj] = w.z; sm.p.Wt[(kk + 3) * 65 + jj] = w.w;
      }
      __syncthreads();
#pragma unroll 4
      for (int k = 0; k < 64; k++) {
        float2 av = *(const float2*)&sm.p.hs[(kl0 + k) * 18 + bq2];
        float wv = sm.p.Wt[k * 65 + jg];
        acc0 += av.x * wv; acc1 += av.y * wv;
      }
    }
    float* pd = kh ? P.praw1 : P.praw0;
    if (j0 + jg < 1572) {
      pd[(size_t)(b0 + bq2 + 0) * kPRow + j0 + jg] = acc0;
      pd[(size_t)(b0 + bq2 + 1) * kPRow + j0 + jg] = acc1;
    }
  }
  barrier_on(P.gcnt, GRID * 2);

  // ============ From here: fully per-batch pipeline (4 blocks per batch) ============
  const int b = bb_;
  const size_t brow = (size_t)b * kN;

  // ---- Stage S (sub 0 only): split params + sdots + zero cat[b][0:384) ----
  if (sub_ == 0) {
    const int m = tid & 127;
    const int hg = tid >> 7;  // 0..3
    const float* pr0 = P.praw0 + (size_t)b * kPRow;
    const float* pr1 = P.praw1 + (size_t)b * kPRow;
    if (tid < 384) P.cat[(size_t)b * kCatW + tid] = 0.f;
    {  // iter 0: heads {W0, W1, W2, R0}
      const bool isw = hg < 3;
      const int base = isw ? hg * 390 : 1170;
      const float* bias = isw ? (P.write_b + hg * 390) : P.read_b;
      const int slot = isw ? hg : 3;
      float kv = pr0[base + m] + pr1[base + m] + bias[m];
      if (isw) {
        P.kwb[((size_t)hg * kB + b) * kM + m] = kv;
        P.evb[((size_t)hg * kB + b) * kM + m] =
            sigm_(pr0[base + 134 + m] + pr1[base + 134 + m] + bias[134 + m]);
        P.avb[((size_t)hg * kB + b) * kM + m] =
            pr0[base + 262 + m] + pr1[base + 262 + m] + bias[262 + m];
      } else {
        P.krb[((size_t)0 * kB + b) * kM + m] = kv;
      }
      float sq = kv * kv;
#pragma unroll
      for (int mm = 1; mm < 64; mm <<= 1) sq += __shfl_xor(sq, mm, 64);
      if ((tid & 63) == 0) sm.s.nred[hg][m >> 6] = sq;
      __syncthreads();
      if (m == 0) {
        float* s = P.scal + ((size_t)slot * kB + b) * 8;
        s[0] = softplus_(pr0[base + 128] + pr1[base + 128] + bias[128]);
        s[1] = sigm_(pr0[base + 129] + pr1[base + 129] + bias[129]);
        s[2] = 1.f + softplus_(pr0[base + 133] + pr1[base + 133] + bias[133]);
        float x0 = pr0[base + 130] + pr1[base + 130] + bias[130];
        float x1 = pr0[base + 131] + pr1[base + 131] + bias[131];
        float x2 = pr0[base + 132] + pr1[base + 132] + bias[132];
        float mx = fmaxf(x0, fmaxf(x1, x2));
        float e0 = expf(x0 - mx), e1 = expf(x1 - mx), e2 = expf(x2 - mx);
        float si = 1.f / (e0 + e1 + e2);
        s[3] = e0 * si; s[4] = e1 * si; s[5] = e2 * si;
        s[6] = sqrtf(sm.s.nred[hg][0] + sm.s.nred[hg][1]);
      }
      __syncthreads();
    }
    {  // iter 1: heads {R1, R2} on hg 0,1
      const int j = (hg < 2) ? hg + 1 : 2;
      const bool act = hg < 2;
      const int base = 1170 + j * 134;
      const float* bias = P.read_b + j * 134;
      const int slot = 3 + j;
      float kv = pr0[base + m] + pr1[base + m] + bias[m];
      if (act) P.krb[((size_t)j * kB + b) * kM + m] = kv;
      float sq = kv * kv;
#pragma unroll
      for (int mm = 1; mm < 64; mm <<= 1) sq += __shfl_xor(sq, mm, 64);
      if ((tid & 63) == 0) sm.s.nred[hg][m >> 6] = sq;
      __syncthreads();
      if (m == 0 && act) {
        float* s = P.scal + ((size_t)slot * kB + b) * 8;
        s[0] = softplus_(pr0[base + 128] + pr1[base + 128] + bias[128]);
        s[1] = sigm_(pr0[base + 129] + pr1[base + 129] + bias[129]);
        s[2] = 1.f + softplus_(pr0[base + 133] + pr1[base + 133] + bias[133]);
        float x0 = pr0[base + 130] + pr1[base + 130] + bias[130];
        float x1 = pr0[base + 131] + pr1[base + 131] + bias[131];
        float x2 = pr0[base + 132] + pr1[base + 132] + bias[132];
        float mx = fmaxf(x0, fmaxf(x1, x2));
        float e0 = expf(x0 - mx), e1 = expf(x1 - mx), e2 = expf(x2 - mx);
        float si = 1.f / (e0 + e1 + e2);
        s[3] = e0 * si; s[4] = e1 * si; s[5] = e2 * si;
        s[6] = sqrtf(sm.s.nred[hg][0] + sm.s.nred[hg][1]);
      }
      __syncthreads();
    }
    // sdots: {a0.kr0, a0.kw1, a0.a0, a2.kr2, a2.a2}
    if (tid < 64) {
      const float* a0v = P.avb + ((size_t)0 * kB + b) * kM;
      const float* a2v = P.avb + ((size_t)2 * kB + b) * kM;
      const float* u[5] = {a0v, a0v, a0v, a2v, a2v};
      const float* v[5] = {P.krb + ((size_t)0 * kB + b) * kM,
                           P.kwb + ((size_t)1 * kB + b) * kM,
                           a0v,
                           P.krb + ((size_t)2 * kB + b) * kM,
                           a2v};
#pragma unroll
      for (int d = 0; d < 5; d++) {
        float s = u[d][tid] * v[d][tid] + u[d][tid + 64] * v[d][tid + 64];
#pragma unroll
        for (int mm = 1; mm < 64; mm <<= 1) s += __shfl_xor(s, mm, 64);
        if (tid == 0) P.sdot[b * 8 + d] = s;
      }
    }
  }
  barrier_on(bc, 4);

  // ---- Pass A: B0 moments (chunk = sub) ----
  {
    const int chunk = sub_;
    const int lane = tid & 63, wv = tid >> 6, sub = lane >> 4, lm = lane & 15;
    const int m8 = lm * 8;
    float kw0r[8], kr0r[8], kw1r[8], a0r[8], e0r[8];
#pragma unroll
    for (int t = 0; t < 8; t++) {
      kw0r[t] = P.kwb[((size_t)0 * kB + b) * kM + m8 + t];
      kr0r[t] = P.krb[((size_t)0 * kB + b) * kM + m8 + t];
      kw1r[t] = P.kwb[((size_t)1 * kB + b) * kM + m8 + t];
      a0r[t]  = P.avb[((size_t)0 * kB + b) * kM + m8 + t];
      e0r[t]  = P.evb[((size_t)0 * kB + b) * kM + m8 + t];
    }
    const size_t bbase = (size_t)b * kN * kM;
    const int row0 = chunk * 1024 + wv * 4 + sub;
    const float* base = P.bank + bbase + (size_t)row0 * kM + m8;
    float4 pA0 = *(const float4*)(base);
    float4 pA1 = *(const float4*)(base + 4);
    float4 pB0 = *(const float4*)(base + (size_t)32 * kM);
    float4 pB1 = *(const float4*)(base + (size_t)32 * kM + 4);
    for (int it = 0; it < 32; it++) {
      float v[8];
      if ((it & 1) == 0) {
        v[0]=pA0.x; v[1]=pA0.y; v[2]=pA0.z; v[3]=pA0.w; v[4]=pA1.x; v[5]=pA1.y; v[6]=pA1.z; v[7]=pA1.w;
        if (it + 2 < 32) {
          const float* np = base + (size_t)(it + 2) * 32 * kM;
          pA0 = *(const float4*)np; pA1 = *(const float4*)(np + 4);
        }
      } else {
        v[0]=pB0.x; v[1]=pB0.y; v[2]=pB0.z; v[3]=pB0.w; v[4]=pB1.x; v[5]=pB1.y; v[6]=pB1.z; v[7]=pB1.w;
        if (it + 2 < 32) {
          const float* np = base + (size_t)(it + 2) * 32 * kM;
          pB0 = *(const float4*)np; pB1 = *(const float4*)(np + 4);
        }
      }
      const int row = row0 + it * 32;
      float s[10] = {};
#pragma unroll
      for (int t = 0; t < 8; t++) {
        float be = v[t] * e0r[t];
        s[0] += v[t] * kw0r[t];
        s[1] += v[t] * v[t];
        s[2] += v[t] * kr0r[t];
        s[3] += be * kr0r[t];
        s[4] += v[t] * kw1r[t];
        s[5] += be * kw1r[t];
        s[6] += be * v[t];
        s[7] += be * be;
        s[8] += v[t] * a0r[t];
        s[9] += be * a0r[t];
      }
#pragma unroll
      for (int m = 1; m < 16; m <<= 1)
#pragma unroll
        for (int k = 0; k < 10; k++) s[k] += __shfl_xor(s[k], m, 64);
      if (lm == 0) {
        float4* dst = (float4*)(P.mA + (size_t)(brow + row) * 12);
        dst[0] = make_float4(s[0], s[1], s[2], s[3]);
        dst[1] = make_float4(s[4], s[5], s[6], s[7]);
        dst[2] = make_float4(s[8], s[9], 0.f, 0.f);
      }
    }
  }
  barrier_on(bc, 8);

  // ---- Stage A12 (subs 0,1): role0: w0 -> wr0; role1: w0(dup) -> w1 ----
  if (sub_ < 2) {
    const int role = sub_;
    float loc[8], w0r[8];
    {  // write head 0 on B0 (both roles compute; role0 stores)
      const float* sc = P.scal + ((size_t)0 * kB + b) * 8;
      const float beta = sc[0], kn = sc[6];
#pragma unroll
      for (int i = 0; i < 8; i++) {
        const float* mp = P.mA + (size_t)(brow + tid + i * TPB) * 12;
        float4 q0 = *(const float4*)mp;
        loc[i] = beta * q0.x / fmaxf(sqrtf(fmaxf(q0.y, 0.f)) * kn, 1e-8f);
      }
      addr_core8(tid, loc, sc, P.write_w_prev + brow, sm.a.wb, sm.a.red);
#pragma unroll
      for (int i = 0; i < 8; i++) {
        w0r[i] = loc[i];
        if (role == 0) P.wp0[brow + tid + i * TPB] = loc[i];
      }
    }
    if (role == 0) {  // read head 0 on B1 (expanded)
      const float* sc = P.scal + ((size_t)3 * kB + b) * 8;
      const float beta = sc[0], kn = sc[6];
      const float sa0kr0 = P.sdot[b * 8 + 0], sa0a0 = P.sdot[b * 8 + 2];
#pragma unroll
      for (int i = 0; i < 8; i++) {
        const float* mp = P.mA + (size_t)(brow + tid + i * TPB) * 12;
        float4 q0 = *(const float4*)mp;
        float4 q1 = *(const float4*)(mp + 4);
        float4 q2 = *(const float4*)(mp + 8);
        float w0 = w0r[i], w0q = w0 * w0;
        float q1v = q0.y - 2.f * w0 * q1.z + w0q * q1.w + 2.f * w0 * q2.x
                  - 2.f * w0q * q2.y + w0q * sa0a0;
        float d = q0.z - w0 * q0.w + w0 * sa0kr0;
        loc[i] = beta * d / fmaxf(sqrtf(fmaxf(q1v, 0.f)) * kn, 1e-8f);
      }
      addr_core8(tid, loc, sc, P.read_w_prev + brow, sm.a.wb, sm.a.red);
#pragma unroll
      for (int i = 0; i < 8; i++) P.wp2[brow + tid + i * TPB] = loc[i];
    } else {  // write head 1 on B1 (expanded; recompute q1v locally)
      const float* sc = P.scal + ((size_t)1 * kB + b) * 8;
      const float beta = sc[0], kn = sc[6];
      const float sa0kw1 = P.sdot[b * 8 + 1], sa0a0 = P.sdot[b * 8 + 2];
#pragma unroll
      for (int i = 0; i < 8; i++) {
        const float* mp = P.mA + (size_t)(brow + tid + i * TPB) * 12;
        float4 q0 = *(const float4*)mp;
        float4 q1 = *(const float4*)(mp + 4);
        float4 q2 = *(const float4*)(mp + 8);
        float w0 = w0r[i], w0q = w0 * w0;
        float q1v = q0.y - 2.f * w0 * q1.z + w0q * q1.w + 2.f * w0 * q2.x
                  - 2.f * w0q * q2.y + w0q * sa0a0;
        float d = q1.x - w0 * q1.y + w0 * sa0kw1;
        loc[i] = beta * d / fmaxf(sqrtf(fmaxf(q1v, 0.f)) * kn, 1e-8f);
      }
      addr_core8(tid, loc, sc, P.write_w_prev + (size_t)kWN + brow, sm.a.wb, sm.a.red);
#pragma unroll
      for (int i = 0; i < 8; i++) P.wp1[brow + tid + i * TPB] = loc[i];
    }
  }
  barrier_on(bc, 12);

  // ---- Pass B: chain(w0,w1), read0, B2 moments ----
  {
    const int chunk = sub_;
    const int lane = tid & 63, wv = tid >> 6, sub = lane >> 4, lm = lane & 15;
    const int m8 = lm * 8;
    float e0r[8], a0r[8], e1r[8], a1r[8], kr1r[8], kw2r[8], kr2r[8], e2r[8], a2r[8];
#pragma unroll
    for (int t = 0; t < 8; t++) {
      e0r[t]  = P.evb[((size_t)0 * kB + b) * kM + m8 + t];
      a0r[t]  = P.avb[((size_t)0 * kB + b) * kM + m8 + t];
      e1r[t]  = P.evb[((size_t)1 * kB + b) * kM + m8 + t];
      a1r[t]  = P.avb[((size_t)1 * kB + b) * kM + m8 + t];
      kr1r[t] = P.krb[((size_t)1 * kB + b) * kM + m8 + t];
      kw2r[t] = P.kwb[((size_t)2 * kB + b) * kM + m8 + t];
      kr2r[t] = P.krb[((size_t)2 * kB + b) * kM + m8 + t];
      e2r[t]  = P.evb[((size_t)2 * kB + b) * kM + m8 + t];
      a2r[t]  = P.avb[((size_t)2 * kB + b) * kM + m8 + t];
    }
    float racc[8] = {};
    if (tid < kM) sm.r.rl[tid] = 0.f;
    const size_t bbase = (size_t)b * kN * kM;
    const int row0 = chunk * 1024 + wv * 4 + sub;
    const float* base = P.bank + bbase + (size_t)row0 * kM + m8;
    const size_t wrow = brow + row0;
    float4 pA0 = *(const float4*)(base);
    float4 pA1 = *(const float4*)(base + 4);
    float4 pB0 = *(const float4*)(base + (size_t)32 * kM);
    float4 pB1 = *(const float4*)(base + (size_t)32 * kM + 4);
    float w0A = P.wp0[wrow], w1A = P.wp1[wrow], r0A = P.wp2[wrow];
    float w0B = P.wp0[wrow + 32], w1B = P.wp1[wrow + 32], r0B = P.wp2[wrow + 32];
    for (int it = 0; it < 32; it++) {
      float v[8];
      float w0, w1, wr0;
      if ((it & 1) == 0) {
        v[0]=pA0.x; v[1]=pA0.y; v[2]=pA0.z; v[3]=pA0.w; v[4]=pA1.x; v[5]=pA1.y; v[6]=pA1.z; v[7]=pA1.w;
        w0 = w0A; w1 = w1A; wr0 = r0A;
        if (it + 2 < 32) {
          const float* np = base + (size_t)(it + 2) * 32 * kM;
          pA0 = *(const float4*)np; pA1 = *(const float4*)(np + 4);
          size_t wn = wrow + (size_t)(it + 2) * 32;
          w0A = P.wp0[wn]; w1A = P.wp1[wn]; r0A = P.wp2[wn];
        }
      } else {
        v[0]=pB0.x; v[1]=pB0.y; v[2]=pB0.z; v[3]=pB0.w; v[4]=pB1.x; v[5]=pB1.y; v[6]=pB1.z; v[7]=pB1.w;
        w0 = w0B; w1 = w1B; wr0 = r0B;
        if (it + 2 < 32) {
          const float* np = base + (size_t)(it + 2) * 32 * kM;
          pB0 = *(const float4*)np; pB1 = *(const float4*)(np + 4);
          size_t wn = wrow + (size_t)(it + 2) * 32;
          w0B = P.wp0[wn]; w1B = P.wp1[wn]; r0B = P.wp2[wn];
        }
      }
      const int row = row0 + it * 32;
#pragma unroll
      for (int t = 0; t < 8; t++) {
        v[t] += w0 * (a0r[t] - e0r[t] * v[t]);  // -> B1
        racc[t] += wr0 * v[t];                   // read0 from B1
        v[t] += w1 * (a1r[t] - e1r[t] * v[t]);  // -> B2
      }
      float s[9] = {};
#pragma unroll
      for (int t = 0; t < 8; t++) {
        float ve = v[t] * e2r[t];
        s[0] += v[t] * kr1r[t];
        s[1] += v[t] * kw2r[t];
        s[2] += v[t] * v[t];
        s[3] += v[t] * kr2r[t];
        s[4] += ve * kr2r[t];
        s[5] += ve * v[t];
        s[6] += ve * ve;
        s[7] += v[t] * a2r[t];
        s[8] += ve * a2r[t];
      }
#pragma unroll
      for (int m = 1; m < 16; m <<= 1)
#pragma unroll
        for (int k = 0; k < 9; k++) s[k] += __shfl_xor(s[k], m, 64);
      if (lm == 0) {
        float4* dst = (float4*)(P.mB + (size_t)(brow + row) * 12);
        dst[0] = make_float4(s[0], s[1], s[2], s[3]);
        dst[1] = make_float4(s[4], s[5], s[6], s[7]);
        dst[2] = make_float4(s[8], 0.f, 0.f, 0.f);
      }
    }
    __syncthreads();
#pragma unroll
    for (int t = 0; t < 8; t++) {
      racc[t] += __shfl_xor(racc[t], 16, 64);
      racc[t] += __shfl_xor(racc[t], 32, 64);
    }
    if (sub == 0) {
#pragma unroll
      for (int t = 0; t < 8; t++) atomicAdd(&sm.r.rl[m8 + t], racc[t]);
    }
    __syncthreads();
    if (tid < kM) atomicAdd(&P.cat[(size_t)b * kCatW + tid], sm.r.rl[tid]);
  }
  barrier_on(bc, 16);

  // ---- Stage A34 (subs 0,1): role0: w2 -> wr2; role1: wr1 ----
  if (sub_ < 2) {
    const int role = sub_;
    float loc[8];
    if (role == 0) {
      float w2r[8];
      {  // write head 2 on B2
        const float* sc = P.scal + ((size_t)2 * kB + b) * 8;
        const float beta = sc[0], kn = sc[6];
#pragma unroll
        for (int i = 0; i < 8; i++) {
          const float* mp = P.mB + (size_t)(brow + tid + i * TPB) * 12;
          float4 q0 = *(const float4*)mp;
          loc[i] = beta * q0.y / fmaxf(sqrtf(fmaxf(q0.z, 0.f)) * kn, 1e-8f);
        }
        addr_core8(tid, loc, sc, P.write_w_prev + (size_t)2 * kWN + brow, sm.a.wb, sm.a.red);
#pragma unroll
        for (int i = 0; i < 8; i++) {
          P.wp3[brow + tid + i * TPB] = loc[i];
          w2r[i] = loc[i];
        }
      }
      {  // read head 2 on B3 (expanded)
        const float* sc = P.scal + ((size_t)5 * kB + b) * 8;
        const float beta = sc[0], kn = sc[6];
        const float sa2kr2 = P.sdot[b * 8 + 3], sa2a2 = P.sdot[b * 8 + 4];
#pragma unroll
        for (int i = 0; i < 8; i++) {
          const float* mp = P.mB + (size_t)(brow + tid + i * TPB) * 12;
          float4 q0 = *(const float4*)mp;
          float4 q1 = *(const float4*)(mp + 4);
          float4 q2 = *(const float4*)(mp + 8);
          float w2 = w2r[i], w2q = w2 * w2;
          float q3 = q0.z - 2.f * w2 * q1.y + w2q * q1.z + 2.f * w2 * q1.w
                   - 2.f * w2q * q2.x + w2q * sa2a2;
          float d = q0.w - w2 * q1.x + w2 * sa2kr2;
          loc[i] = beta * d / fmaxf(sqrtf(fmaxf(q3, 0.f)) * kn, 1e-8f);
        }
        addr_core8(tid, loc, sc, P.read_w_prev + (size_t)2 * kWN + brow, sm.a.wb, sm.a.red);
#pragma unroll
        for (int i = 0; i < 8; i++) P.wp5[brow + tid + i * TPB] = loc[i];
      }
    } else {
      {  // read head 1 on B2 (independent of w2)
        const float* sc = P.scal + ((size_t)4 * kB + b) * 8;
        const float beta = sc[0], kn = sc[6];
#pragma unroll
        for (int i = 0; i < 8; i++) {
          const float* mp = P.mB + (size_t)(brow + tid + i * TPB) * 12;
          float4 q0 = *(const float4*)mp;
          loc[i] = beta * q0.x / fmaxf(sqrtf(fmaxf(q0.z, 0.f)) * kn, 1e-8f);
        }
        addr_core8(tid, loc, sc, P.read_w_prev + (size_t)kWN + brow, sm.a.wb, sm.a.red);
#pragma unroll
        for (int i = 0; i < 8; i++) P.wp4[brow + tid + i * TPB] = loc[i];
      }
    }
  }
  barrier_on(bc, 20);

  // ---- Pass C: chain(w0,w1,w2), read1 from B2, read2 from B3 ----
  {
    const int chunk = sub_;
    const int lane = tid & 63, wv = tid >> 6, sub = lane >> 4, lm = lane & 15;
    const int m8 = lm * 8;
    float e_r[3][8], a_r[3][8];
#pragma unroll
    for (int j = 0; j < 3; j++)
#pragma unroll
      for (int t = 0; t < 8; t++) {
        e_r[j][t] = P.evb[((size_t)j * kB + b) * kM + m8 + t];
        a_r[j][t] = P.avb[((size_t)j * kB + b) * kM + m8 + t];
      }
    float racc1[8] = {}, racc2[8] = {};
    if (tid < kM) { sm.r.rl[tid] = 0.f; sm.r.rl[kM + tid] = 0.f; }
    const size_t bbase = (size_t)b * kN * kM;
    const int row0 = chunk * 1024 + wv * 4 + sub;
    const float* base = P.bank + bbase + (size_t)row0 * kM + m8;
    const size_t wrow = brow + row0;
    float4 pA0 = *(const float4*)(base);
    float4 pA1 = *(const float4*)(base + 4);
    float4 pB0 = *(const float4*)(base + (size_t)32 * kM);
    float4 pB1 = *(const float4*)(base + (size_t)32 * kM + 4);
    float c0A = P.wp0[wrow], c1A = P.wp1[wrow], c2A = P.wp3[wrow], c3A = P.wp4[wrow], c4A = P.wp5[wrow];
    float c0B = P.wp0[wrow + 32], c1B = P.wp1[wrow + 32], c2B = P.wp3[wrow + 32],
          c3B = P.wp4[wrow + 32], c4B = P.wp5[wrow + 32];
    for (int it = 0; it < 32; it++) {
      float v[8];
      float w0, w1, w2, wr1, wr2;
      if ((it & 1) == 0) {
        v[0]=pA0.x; v[1]=pA0.y; v[2]=pA0.z; v[3]=pA0.w; v[4]=pA1.x; v[5]=pA1.y; v[6]=pA1.z; v[7]=pA1.w;
        w0 = c0A; w1 = c1A; w2 = c2A; wr1 = c3A; wr2 = c4A;
        if (it + 2 < 32) {
          const float* np = base + (size_t)(it + 2) * 32 * kM;
          pA0 = *(const float4*)np; pA1 = *(const float4*)(np + 4);
          size_t wn = wrow + (size_t)(it + 2) * 32;
          c0A = P.wp0[wn]; c1A = P.wp1[wn]; c2A = P.wp3[wn]; c3A = P.wp4[wn]; c4A = P.wp5[wn];
        }
      } else {
        v[0]=pB0.x; v[1]=pB0.y; v[2]=pB0.z; v[3]=pB0.w; v[4]=pB1.x; v[5]=pB1.y; v[6]=pB1.z; v[7]=pB1.w;
        w0 = c0B; w1 = c1B; w2 = c2B; wr1 = c3B; wr2 = c4B;
        if (it + 2 < 32) {
          const float* np = base + (size_t)(it + 2) * 32 * kM;
          pB0 = *(const float4*)np; pB1 = *(const float4*)(np + 4);
          size_t wn = wrow + (size_t)(it + 2) * 32;
          c0B = P.wp0[wn]; c1B = P.wp1[wn]; c2B = P.wp3[wn]; c3B = P.wp4[wn]; c4B = P.wp5[wn];
        }
      }
#pragma unroll
      for (int t = 0; t < 8; t++) {
        v[t] += w0 * (a_r[0][t] - e_r[0][t] * v[t]);  // B1
        v[t] += w1 * (a_r[1][t] - e_r[1][t] * v[t]);  // B2
        racc1[t] += wr1 * v[t];
        v[t] += w2 * (a_r[2][t] - e_r[2][t] * v[t]);  // B3
        racc2[t] += wr2 * v[t];
      }
    }
    __syncthreads();
#pragma unroll
    for (int t = 0; t < 8; t++) {
      racc1[t] += __shfl_xor(racc1[t], 16, 64);
      racc1[t] += __shfl_xor(racc1[t], 32, 64);
      racc2[t] += __shfl_xor(racc2[t], 16, 64);
      racc2[t] += __shfl_xor(racc2[t], 32, 64);
    }
    if (sub == 0) {
#pragma unroll
      for (int t = 0; t < 8; t++) {
        atomicAdd(&sm.r.rl[m8 + t], racc1[t]);
        atomicAdd(&sm.r.rl[kM + m8 + t], racc2[t]);
      }
    }
    __syncthreads();
    if (tid < kM) {
      atomicAdd(&P.cat[(size_t)b * kCatW + kM + tid], sm.r.rl[tid]);
      atomicAdd(&P.cat[(size_t)b * kCatW + 2 * kM + tid], sm.r.rl[kM + tid]);
    }
  }
  barrier_on(bc, 24);

  // ---- Phase O: per-batch out rows (no atomics): block sub covers 64 j's ----
  {
    const int j = sub_ * 64 + (tid >> 3);
    const int ks = (tid & 7) * 112;
    const float* crow = P.cat + (size_t)b * kCatW;
    const float* wrow = P.out_W + (size_t)j * kCatW;
    float acc = 0.f;
#pragma unroll 7
    for (int k = 0; k < 112; k += 4) {
      float4 cv = *(const float4*)(crow + ks + k);
      float4 wv = *(const float4*)(wrow + ks + k);
      acc += cv.x * wv.x + cv.y * wv.y + cv.z * wv.z + cv.w * wv.w;
    }
    acc += __shfl_xor(acc, 1, 64);
    acc += __shfl_xor(acc, 2, 64);
    acc += __shfl_xor(acc, 4, 64);
    if ((tid & 7) == 0) P.out[(size_t)b * kO + j] = P.out_b[j] + acc;
  }
}

}  // namespace

extern "C" void kernel_launch(void* const* d_in, const int* in_sizes, int n_in,
                              void* d_out, int out_size, void* d_ws, size_t ws_size,
                              hipStream_t stream) {
  Args A_;
  A_.x            = (const float*)d_in[0];
  A_.h_prev       = (const float*)d_in[1];
  A_.c_prev       = (const float*)d_in[2];
  A_.bank         = (const float*)d_in[3];
  A_.read_w_prev  = (const float*)d_in[4];
  A_.write_w_prev = (const float*)d_in[5];
  A_.W_ih         = (const float*)d_in[6];
  A_.W_hh         = (const float*)d_in[7];
  A_.b_ih         = (const float*)d_in[8];
  A_.b_hh         = (const float*)d_in[9];
  A_.read_W       = (const float*)d_in[10];
  A_.read_b       = (const float*)d_in[11];
  A_.write_W      = (const float*)d_in[12];
  A_.write_b      = (const float*)d_in[13];
  A_.out_W        = (const float*)d_in[14];
  A_.out_b        = (const float*)d_in[15];
  A_.out = (float*)d_out;

  float* ws = (float*)d_ws;
  A_.gcnt = (unsigned*)d_ws;            // [0]: global barrier counter
  A_.bcnt = (unsigned*)d_ws + 64;       // 64 batches x 32-u32 stride (128 B each)
  float* p = ws + 4096;                 // data starts at +16 KB (zeroed region)
  A_.gates0 = p; p += (size_t)kB * kGates;
  A_.gates1 = p; p += (size_t)kB * kGates;
  A_.praw0  = p; p += (size_t)kB * kPRow;
  A_.praw1  = p; p += (size_t)kB * kPRow;
  A_.cat    = p; p += (size_t)kB * kCatW;
  A_.kwb    = p; p += (size_t)3 * kB * kM;
  A_.krb    = p; p += (size_t)3 * kB * kM;
  A_.evb    = p; p += (size_t)3 * kB * kM;
  A_.avb    = p; p += (size_t)3 * kB * kM;
  A_.scal   = p; p += (size_t)6 * kB * 8;
  A_.sdot   = p; p += (size_t)kB * 8;
  A_.wp0    = p; p += (size_t)kWN;
  A_.wp1    = p; p += (size_t)kWN;
  A_.wp2    = p; p += (size_t)kWN;
  A_.wp3    = p; p += (size_t)kWN;
  A_.wp4    = p; p += (size_t)kWN;
  A_.wp5    = p; p += (size_t)kWN;
  A_.mA     = p; p += (size_t)kWN * 12;
  A_.mB     = p; p += (size_t)kWN * 12;

  hipMemsetAsync(d_ws, 0, 16384, stream);
  mega<<<dim3(GRID), dim3(TPB), 0, stream>>>(A_);

  (void)in_sizes; (void)n_in; (void)out_size; (void)ws_size;
}